// Round 2
// baseline (13777.486 us; speedup 1.0000x reference)
//
#include <hip/hip_runtime.h>
#include <hip/hip_bf16.h>

// W [Cout,Cin] -> Wt [Cin,Cout]
__global__ void k_transpose(const float* __restrict__ W, float* __restrict__ Wt,
                            int Cin, int Cout) {
    int i = blockIdx.x * blockDim.x + threadIdx.x;
    if (i >= Cin * Cout) return;
    int k = i / Cout, c = i - k * Cout;
    Wt[i] = W[c * Cin + k];
}

// agg[dst[e], :] += x[src[e], :]  -- 4 channels per thread
__global__ void k_scatter(const float* __restrict__ x, const int* __restrict__ src,
                          const int* __restrict__ dst, float* __restrict__ agg,
                          int E, int lgg /* log2(C/4) */) {
    long tid = (long)blockIdx.x * blockDim.x + threadIdx.x;
    long total = (long)E << lgg;
    if (tid >= total) return;
    int e = (int)(tid >> lgg);
    int g = (((int)tid) & ((1 << lgg) - 1)) << 2;
    int C = 4 << lgg;
    int s = src[e], d = dst[e];
    const float4 xv = *reinterpret_cast<const float4*>(x + (long)s * C + g);
    float* ar = agg + (long)d * C + g;
    unsafeAtomicAdd(ar + 0, xv.x);
    unsafeAtomicAdd(ar + 1, xv.y);
    unsafeAtomicAdd(ar + 2, xv.z);
    unsafeAtomicAdd(ar + 3, xv.w);
}

// h[n,c4..c4+3] = sum_k (x[n,k]+agg[n,k]) * Wt[k,c] + b[c]
template <bool RELU>
__global__ void k_linear(const float* __restrict__ x, const float* __restrict__ agg,
                         const float* __restrict__ Wt, const float* __restrict__ bias,
                         float* __restrict__ out, int N, int Cin, int lgCout) {
    int idx = blockIdx.x * blockDim.x + threadIdx.x;
    int Cout = 1 << lgCout;
    int q = Cout >> 2;
    if (idx >= N * q) return;
    int n = idx >> (lgCout - 2);
    int c4 = (idx & (q - 1)) << 2;
    const float* xr = x + (long)n * Cin;
    const float* ar = agg + (long)n * Cin;
    float a0 = bias[c4 + 0];
    float a1 = bias[c4 + 1];
    float a2 = bias[c4 + 2];
    float a3 = bias[c4 + 3];
    const float* wp = Wt + c4;
    for (int k = 0; k < Cin; k += 4) {
        float4 xv = *reinterpret_cast<const float4*>(xr + k);
        float4 av = *reinterpret_cast<const float4*>(ar + k);
        float s0 = xv.x + av.x, s1 = xv.y + av.y, s2 = xv.z + av.z, s3 = xv.w + av.w;
        float4 w0 = *reinterpret_cast<const float4*>(wp + ((long)(k + 0) << lgCout));
        float4 w1 = *reinterpret_cast<const float4*>(wp + ((long)(k + 1) << lgCout));
        float4 w2 = *reinterpret_cast<const float4*>(wp + ((long)(k + 2) << lgCout));
        float4 w3 = *reinterpret_cast<const float4*>(wp + ((long)(k + 3) << lgCout));
        a0 = fmaf(s0, w0.x, a0); a1 = fmaf(s0, w0.y, a1); a2 = fmaf(s0, w0.z, a2); a3 = fmaf(s0, w0.w, a3);
        a0 = fmaf(s1, w1.x, a0); a1 = fmaf(s1, w1.y, a1); a2 = fmaf(s1, w1.z, a2); a3 = fmaf(s1, w1.w, a3);
        a0 = fmaf(s2, w2.x, a0); a1 = fmaf(s2, w2.y, a1); a2 = fmaf(s2, w2.z, a2); a3 = fmaf(s2, w2.w, a3);
        a0 = fmaf(s3, w3.x, a0); a1 = fmaf(s3, w3.y, a1); a2 = fmaf(s3, w3.z, a2); a3 = fmaf(s3, w3.w, a3);
    }
    if (RELU) {
        a0 = fmaxf(a0, 0.f); a1 = fmaxf(a1, 0.f); a2 = fmaxf(a2, 0.f); a3 = fmaxf(a3, 0.f);
    }
    *reinterpret_cast<float4*>(out + ((long)n << lgCout) + c4) = make_float4(a0, a1, a2, a3);
}

// per-channel sum / sumsq partials -> atomics into stats[0..C) and stats[C..2C)
__global__ void k_bnstats(const float* __restrict__ h, float* __restrict__ stats,
                          int N, int C) {
    int tid = blockIdx.x * blockDim.x + threadIdx.x;
    int T = gridDim.x * blockDim.x;
    int c = tid & (C - 1);
    int chunk = tid / C;
    int nch = T / C;
    float s = 0.f, s2 = 0.f;
    for (int n = chunk; n < N; n += nch) {
        float v = h[(long)n * C + c];
        s += v;
        s2 = fmaf(v, v, s2);
    }
    unsafeAtomicAdd(&stats[c], s);
    unsafeAtomicAdd(&stats[C + c], s2);
}

// stats[2C+c]=g*rsqrt(v+eps), stats[3C+c]=beta-m*scale
__global__ void k_bnfin(float* __restrict__ stats, const float* __restrict__ g,
                        const float* __restrict__ beta, int C, float invN) {
    int c = threadIdx.x;
    if (c >= C) return;
    float m = stats[c] * invN;
    float v = stats[C + c] * invN - m * m;
    float sc = g[c] * rsqrtf(v + 1e-5f);
    stats[2 * C + c] = sc;
    stats[3 * C + c] = beta[c] - m * sc;
}

// y = relu(h*scale + shift)
__global__ void k_bnapply(const float* __restrict__ h, const float* __restrict__ stats,
                          float* __restrict__ y, int N, int lgC) {
    int idx = blockIdx.x * blockDim.x + threadIdx.x;
    int C = 1 << lgC;
    int q = C >> 2;
    if (idx >= N * q) return;
    int n = idx >> (lgC - 2);
    int c4 = (idx & (q - 1)) << 2;
    const float4 hv = *reinterpret_cast<const float4*>(h + ((long)n << lgC) + c4);
    const float4 sc = *reinterpret_cast<const float4*>(stats + 2 * C + c4);
    const float4 sh = *reinterpret_cast<const float4*>(stats + 3 * C + c4);
    float4 o;
    o.x = fmaxf(fmaf(hv.x, sc.x, sh.x), 0.f);
    o.y = fmaxf(fmaf(hv.y, sc.y, sh.y), 0.f);
    o.z = fmaxf(fmaf(hv.z, sc.z, sh.z), 0.f);
    o.w = fmaxf(fmaf(hv.w, sc.w, sh.w), 0.f);
    *reinterpret_cast<float4*>(y + ((long)n << lgC) + c4) = o;
}

static inline int cdiv(long a, int b) { return (int)((a + b - 1) / b); }

extern "C" void kernel_launch(void* const* d_in, const int* in_sizes, int n_in,
                              void* d_out, int out_size, void* d_ws, size_t ws_size,
                              hipStream_t stream) {
    const float* ft0 = (const float*)d_in[0];
    const float* ft1 = (const float*)d_in[1];
    const float* fs  = (const float*)d_in[2];
    const int* et0 = (const int*)d_in[3];
    const int* et1 = (const int*)d_in[4];
    const int* es  = (const int*)d_in[5];
    const float* aT0_W = (const float*)d_in[6];
    const float* aT0_b = (const float*)d_in[7];
    const float* aT0_g = (const float*)d_in[8];
    const float* aT0_be = (const float*)d_in[9];
    const float* aT1_W = (const float*)d_in[10];
    const float* aT1_b = (const float*)d_in[11];
    const float* aT1_g = (const float*)d_in[12];
    const float* aT1_be = (const float*)d_in[13];
    const float* aS_W = (const float*)d_in[14];
    const float* aS_b = (const float*)d_in[15];
    const float* aS_g = (const float*)d_in[16];
    const float* aS_be = (const float*)d_in[17];
    const float* ext_W = (const float*)d_in[18];
    const float* ext_b = (const float*)d_in[19];
    const float* ext_g = (const float*)d_in[20];
    const float* ext_be = (const float*)d_in[21];
    const float* rT0_W = (const float*)d_in[22];
    const float* rT0_b = (const float*)d_in[23];
    const float* rT1_W = (const float*)d_in[24];
    const float* rT1_b = (const float*)d_in[25];

    const int N = in_sizes[0] / 256;
    const int E = in_sizes[3] / 2;

    float* out = (float*)d_out;
    // output layout (fp32 elements): hs@0 [N*64], ht(h0,h1)@N*64 [2N*64], f0@N*192 [N*256], f1@N*448 [N*128]
    float* o_hs = out;
    float* o_h0 = out + (long)N * 64;
    float* o_h1 = out + (long)N * 128;
    float* o_f0 = out + (long)N * 192;
    float* o_f1 = out + (long)N * 448;

    // layer-1 activations live in the (not yet written) f0/f1 output regions
    float* A0 = o_f0;                    // N*128
    float* A1 = o_f0 + (long)N * 128;    // N*128
    float* AS = o_f1;                    // N*128

    // workspace: AGG (N*256 f32) + H (N*128 f32) + transposed weights + stats
    char* p = (char*)d_ws;
    float* AGG = (float*)p;   p += (size_t)N * 256 * 4;
    float* H   = (float*)p;   p += (size_t)N * 128 * 4;
    float* aT0t = (float*)p;  p += 256 * 128 * 4;
    float* aT1t = (float*)p;  p += 128 * 128 * 4;
    float* aSt  = (float*)p;  p += 256 * 128 * 4;
    float* extt = (float*)p;  p += 128 * 64 * 4;
    float* rT0t = (float*)p;  p += 64 * 256 * 4;
    float* rT1t = (float*)p;  p += 64 * 128 * 4;
    float* STATS = (float*)p; p += 4 * 128 * 4;

    auto T = [&](const float* W, float* Wt, int Cin, int Cout) {
        int tot = Cin * Cout;
        k_transpose<<<cdiv(tot, 256), 256, 0, stream>>>(W, Wt, Cin, Cout);
    };
    T(aT0_W, aT0t, 256, 128);
    T(aT1_W, aT1t, 128, 128);
    T(aS_W, aSt, 256, 128);
    T(ext_W, extt, 128, 64);
    T(rT0_W, rT0t, 64, 256);
    T(rT1_W, rT1t, 64, 128);

    auto scatter = [&](const float* x, const int* edge, int Cin) {
        hipMemsetAsync(AGG, 0, (size_t)N * Cin * 4, stream);
        int lgg = (Cin == 256) ? 6 : (Cin == 128) ? 5 : 4;
        long tot = (long)E << lgg;
        k_scatter<<<cdiv(tot, 256), 256, 0, stream>>>(x, edge, edge + E, AGG, E, lgg);
    };

    auto gin_bn = [&](const float* x, const int* edge, const float* Wt, const float* b,
                      const float* g, const float* be, int Cin, int lgCout, float* y) {
        int Cout = 1 << lgCout;
        scatter(x, edge, Cin);
        int tot = N * (Cout >> 2);
        k_linear<false><<<cdiv(tot, 256), 256, 0, stream>>>(x, AGG, Wt, b, H, N, Cin, lgCout);
        hipMemsetAsync(STATS, 0, 2 * Cout * 4, stream);
        k_bnstats<<<1024, 256, 0, stream>>>(H, STATS, N, Cout);
        k_bnfin<<<1, Cout, 0, stream>>>(STATS, g, be, Cout, 1.0f / N);
        k_bnapply<<<cdiv(tot, 256), 256, 0, stream>>>(H, STATS, y, N, lgCout);
    };

    auto gin_relu = [&](const float* x, const int* edge, const float* Wt, const float* b,
                        int Cin, int lgCout, float* y) {
        int Cout = 1 << lgCout;
        scatter(x, edge, Cin);
        int tot = N * (Cout >> 2);
        k_linear<true><<<cdiv(tot, 256), 256, 0, stream>>>(x, AGG, Wt, b, y, N, Cin, lgCout);
    };

    // layer 1: align blocks
    gin_bn(ft0, et0, aT0t, aT0_b, aT0_g, aT0_be, 256, 7, A0);
    gin_bn(ft1, et1, aT1t, aT1_b, aT1_g, aT1_be, 128, 7, A1);
    gin_bn(fs,  es,  aSt,  aS_b,  aS_g,  aS_be,  256, 7, AS);

    // layer 2: shared extractor
    gin_bn(A0, et0, extt, ext_b, ext_g, ext_be, 128, 6, o_h0);
    gin_bn(A1, et1, extt, ext_b, ext_g, ext_be, 128, 6, o_h1);
    gin_bn(AS, es,  extt, ext_b, ext_g, ext_be, 128, 6, o_hs);

    // layer 3: recon blocks (Linear + ReLU, no BN) -- overwrite A0/A1/AS (dead)
    gin_relu(o_h0, et0, rT0t, rT0_b, 64, 8, o_f0);
    gin_relu(o_h1, et1, rT1t, rT1_b, 64, 7, o_f1);
}

// Round 3
// 2619.501 us; speedup vs baseline: 5.2596x; 5.2596x over previous
//
#include <hip/hip_runtime.h>
#include <hip/hip_bf16.h>

// ---------- weight transpose: W [Cout,Cin] -> Wt [Cin,Cout] ----------
__global__ void k_transpose(const float* __restrict__ W, float* __restrict__ Wt,
                            int Cin, int Cout) {
    int i = blockIdx.x * blockDim.x + threadIdx.x;
    if (i >= Cin * Cout) return;
    int k = i / Cout, c = i - k * Cout;
    Wt[i] = W[c * Cin + k];
}

// ---------- CSR build ----------
__global__ void k_hist(const int* __restrict__ dst, int* __restrict__ deg, int E) {
    int e = blockIdx.x * blockDim.x + threadIdx.x;
    if (e < E) atomicAdd(&deg[dst[e]], 1);
}

// single-block exclusive scan: deg[N] -> rowptr[N+1]
__global__ void k_scan(const int* __restrict__ deg, int* __restrict__ rowptr, int N) {
    __shared__ int tmp[1024];
    int tid = threadIdx.x;
    int chunk = (N + 1023) >> 10;
    int start = tid * chunk;
    int local = 0;
    for (int i = 0; i < chunk; ++i) {
        int idx = start + i;
        if (idx < N) local += deg[idx];
    }
    tmp[tid] = local;
    __syncthreads();
    for (int off = 1; off < 1024; off <<= 1) {
        int v = tmp[tid];
        if (tid >= off) v += tmp[tid - off];
        __syncthreads();
        tmp[tid] = v;
        __syncthreads();
    }
    int run = tmp[tid] - local;   // exclusive offset for this thread's range
    for (int i = 0; i < chunk; ++i) {
        int idx = start + i;
        if (idx < N) {
            rowptr[idx] = run;
            run += deg[idx];
        }
    }
    if (tid == 1023) rowptr[N] = tmp[1023];
}

__global__ void k_fill(const int* __restrict__ src, const int* __restrict__ dst,
                       int* __restrict__ cursor, int* __restrict__ srcs, int E) {
    int e = blockIdx.x * blockDim.x + threadIdx.x;
    if (e >= E) return;
    int pos = atomicAdd(&cursor[dst[e]], 1);
    srcs[pos] = src[e];
}

// ---------- fused gather + linear ----------
// one 64-thread group per node: gather x[n]+sum_{e: dst==n} x[src[e]] into LDS,
// then h[n,:] = s @ Wt + b  (optionally ReLU).
template <int NCI, int NCO, bool RELU>
__global__ void k_gin(const float* __restrict__ x, const int* __restrict__ rowptr,
                      const int* __restrict__ srcs, const float* __restrict__ Wt,
                      const float* __restrict__ bias, float* __restrict__ out, int N) {
    constexpr int CIN = NCI * 64;
    constexpr int COUT = NCO * 64;
    __shared__ float s[4][CIN];
    int l = threadIdx.x & 63;
    int g = threadIdx.x >> 6;
    int n = blockIdx.x * 4 + g;
    if (n < N) {
        float acc[NCI];
        const float* xr = x + (long)n * CIN;
#pragma unroll
        for (int i = 0; i < NCI; ++i) acc[i] = xr[l + i * 64];
        int p1 = rowptr[n + 1];
        for (int p = rowptr[n]; p < p1; ++p) {
            const float* sr = x + (long)srcs[p] * CIN;
#pragma unroll
            for (int i = 0; i < NCI; ++i) acc[i] += sr[l + i * 64];
        }
#pragma unroll
        for (int i = 0; i < NCI; ++i) s[g][l + i * 64] = acc[i];
    }
    __syncthreads();
    if (n >= N) return;
    float h[NCO];
#pragma unroll
    for (int j = 0; j < NCO; ++j) h[j] = bias[l + j * 64];
    const float* wp = Wt + l;
#pragma unroll 4
    for (int k = 0; k < CIN; ++k) {
        float sv = s[g][k];
#pragma unroll
        for (int j = 0; j < NCO; ++j)
            h[j] = fmaf(sv, wp[(long)k * COUT + j * 64], h[j]);
    }
    float* orow = out + (long)n * COUT;
#pragma unroll
    for (int j = 0; j < NCO; ++j) {
        float v = h[j];
        if (RELU) v = fmaxf(v, 0.f);
        orow[l + j * 64] = v;
    }
}

// ---------- BN ----------
__global__ void k_bnstats(const float* __restrict__ h, float* __restrict__ stats,
                          int N, int C) {
    int tid = blockIdx.x * blockDim.x + threadIdx.x;
    int T = gridDim.x * blockDim.x;
    int c = tid & (C - 1);
    int chunk = tid / C;
    int nch = T / C;
    float s = 0.f, s2 = 0.f;
    for (int n = chunk; n < N; n += nch) {
        float v = h[(long)n * C + c];
        s += v;
        s2 = fmaf(v, v, s2);
    }
    unsafeAtomicAdd(&stats[c], s);
    unsafeAtomicAdd(&stats[C + c], s2);
}

__global__ void k_bnfin(float* __restrict__ stats, const float* __restrict__ g,
                        const float* __restrict__ beta, int C, float invN) {
    int c = threadIdx.x;
    if (c >= C) return;
    float m = stats[c] * invN;
    float v = stats[C + c] * invN - m * m;
    float sc = g[c] * rsqrtf(v + 1e-5f);
    stats[2 * C + c] = sc;
    stats[3 * C + c] = beta[c] - m * sc;
}

__global__ void k_bnapply(const float* __restrict__ h, const float* __restrict__ stats,
                          float* __restrict__ y, int N, int lgC) {
    int idx = blockIdx.x * blockDim.x + threadIdx.x;
    int C = 1 << lgC;
    int q = C >> 2;
    if (idx >= N * q) return;
    int n = idx >> (lgC - 2);
    int c4 = (idx & (q - 1)) << 2;
    const float4 hv = *reinterpret_cast<const float4*>(h + ((long)n << lgC) + c4);
    const float4 sc = *reinterpret_cast<const float4*>(stats + 2 * C + c4);
    const float4 sh = *reinterpret_cast<const float4*>(stats + 3 * C + c4);
    float4 o;
    o.x = fmaxf(fmaf(hv.x, sc.x, sh.x), 0.f);
    o.y = fmaxf(fmaf(hv.y, sc.y, sh.y), 0.f);
    o.z = fmaxf(fmaf(hv.z, sc.z, sh.z), 0.f);
    o.w = fmaxf(fmaf(hv.w, sc.w, sh.w), 0.f);
    *reinterpret_cast<float4*>(y + ((long)n << lgC) + c4) = o;
}

static inline int cdiv(long a, int b) { return (int)((a + b - 1) / b); }

extern "C" void kernel_launch(void* const* d_in, const int* in_sizes, int n_in,
                              void* d_out, int out_size, void* d_ws, size_t ws_size,
                              hipStream_t stream) {
    const float* ft0 = (const float*)d_in[0];
    const float* ft1 = (const float*)d_in[1];
    const float* fs  = (const float*)d_in[2];
    const int* et0 = (const int*)d_in[3];
    const int* et1 = (const int*)d_in[4];
    const int* es  = (const int*)d_in[5];
    const float* aT0_W = (const float*)d_in[6];
    const float* aT0_b = (const float*)d_in[7];
    const float* aT0_g = (const float*)d_in[8];
    const float* aT0_be = (const float*)d_in[9];
    const float* aT1_W = (const float*)d_in[10];
    const float* aT1_b = (const float*)d_in[11];
    const float* aT1_g = (const float*)d_in[12];
    const float* aT1_be = (const float*)d_in[13];
    const float* aS_W = (const float*)d_in[14];
    const float* aS_b = (const float*)d_in[15];
    const float* aS_g = (const float*)d_in[16];
    const float* aS_be = (const float*)d_in[17];
    const float* ext_W = (const float*)d_in[18];
    const float* ext_b = (const float*)d_in[19];
    const float* ext_g = (const float*)d_in[20];
    const float* ext_be = (const float*)d_in[21];
    const float* rT0_W = (const float*)d_in[22];
    const float* rT0_b = (const float*)d_in[23];
    const float* rT1_W = (const float*)d_in[24];
    const float* rT1_b = (const float*)d_in[25];

    const int N = in_sizes[0] / 256;
    const int E = in_sizes[3] / 2;

    float* out = (float*)d_out;
    float* o_hs = out;                      // [N,64]
    float* o_h0 = out + (long)N * 64;       // [N,64]
    float* o_h1 = out + (long)N * 128;      // [N,64]
    float* o_f0 = out + (long)N * 192;      // [N,256]
    float* o_f1 = out + (long)N * 448;      // [N,128]

    // layer-1 activations live in the (not yet written) f0/f1 output regions
    float* A0 = o_f0;                       // [N,128]
    float* A1 = o_f0 + (long)N * 128;       // [N,128]
    float* AS = o_f1;                       // [N,128]

    // workspace
    char* p = (char*)d_ws;
    float* H = (float*)p;      p += (size_t)N * 128 * 4;
    int* rp0 = (int*)p;        p += (size_t)(N + 1) * 4;
    int* rp1 = (int*)p;        p += (size_t)(N + 1) * 4;
    int* rps = (int*)p;        p += (size_t)(N + 1) * 4;
    int* sr0 = (int*)p;        p += (size_t)E * 4;
    int* sr1 = (int*)p;        p += (size_t)E * 4;
    int* srs = (int*)p;        p += (size_t)E * 4;
    int* scratchN = (int*)p;   p += (size_t)N * 4;    // deg, then cursor
    float* aT0t = (float*)p;   p += 256 * 128 * 4;
    float* aT1t = (float*)p;   p += 128 * 128 * 4;
    float* aSt  = (float*)p;   p += 256 * 128 * 4;
    float* extt = (float*)p;   p += 128 * 64 * 4;
    float* rT0t = (float*)p;   p += 64 * 256 * 4;
    float* rT1t = (float*)p;   p += 64 * 128 * 4;
    float* STATS = (float*)p;  p += 4 * 128 * 4;

    // ---- CSR builds (3) ----
    auto buildCSR = [&](const int* edge, int* rowptr, int* srcs) {
        const int* src = edge;
        const int* dst = edge + E;
        hipMemsetAsync(scratchN, 0, (size_t)N * 4, stream);
        k_hist<<<cdiv(E, 256), 256, 0, stream>>>(dst, scratchN, E);
        k_scan<<<1, 1024, 0, stream>>>(scratchN, rowptr, N);
        hipMemcpyAsync(scratchN, rowptr, (size_t)N * 4, hipMemcpyDeviceToDevice, stream);
        k_fill<<<cdiv(E, 256), 256, 0, stream>>>(src, dst, scratchN, srcs, E);
    };
    buildCSR(et0, rp0, sr0);
    buildCSR(et1, rp1, sr1);
    buildCSR(es, rps, srs);

    // ---- weight transposes ----
    auto T = [&](const float* W, float* Wt, int Cin, int Cout) {
        int tot = Cin * Cout;
        k_transpose<<<cdiv(tot, 256), 256, 0, stream>>>(W, Wt, Cin, Cout);
    };
    T(aT0_W, aT0t, 256, 128);
    T(aT1_W, aT1t, 128, 128);
    T(aS_W, aSt, 256, 128);
    T(ext_W, extt, 128, 64);
    T(rT0_W, rT0t, 64, 256);
    T(rT1_W, rT1t, 64, 128);

    // ---- fused GIN dispatch ----
    auto gin = [&](const float* x, const int* rowptr, const int* srcs,
                   const float* Wt, const float* b, float* y, int Cin, int Cout) {
        int blocks = cdiv(N, 4);
        if (Cin == 256 && Cout == 128)
            k_gin<4, 2, false><<<blocks, 256, 0, stream>>>(x, rowptr, srcs, Wt, b, y, N);
        else if (Cin == 128 && Cout == 128)
            k_gin<2, 2, false><<<blocks, 256, 0, stream>>>(x, rowptr, srcs, Wt, b, y, N);
        else if (Cin == 128 && Cout == 64)
            k_gin<2, 1, false><<<blocks, 256, 0, stream>>>(x, rowptr, srcs, Wt, b, y, N);
        else if (Cin == 64 && Cout == 256)
            k_gin<1, 4, true><<<blocks, 256, 0, stream>>>(x, rowptr, srcs, Wt, b, y, N);
        else if (Cin == 64 && Cout == 128)
            k_gin<1, 2, true><<<blocks, 256, 0, stream>>>(x, rowptr, srcs, Wt, b, y, N);
    };

    auto gin_bn = [&](const float* x, const int* rowptr, const int* srcs,
                      const float* Wt, const float* b, const float* g, const float* be,
                      int Cin, int lgCout, float* y) {
        int Cout = 1 << lgCout;
        gin(x, rowptr, srcs, Wt, b, H, Cin, Cout);
        hipMemsetAsync(STATS, 0, 2 * Cout * 4, stream);
        k_bnstats<<<1024, 256, 0, stream>>>(H, STATS, N, Cout);
        k_bnfin<<<1, Cout, 0, stream>>>(STATS, g, be, Cout, 1.0f / N);
        k_bnapply<<<cdiv((long)N * (Cout >> 2), 256), 256, 0, stream>>>(H, STATS, y, N, lgCout);
    };

    // layer 1: align blocks
    gin_bn(ft0, rp0, sr0, aT0t, aT0_b, aT0_g, aT0_be, 256, 7, A0);
    gin_bn(ft1, rp1, sr1, aT1t, aT1_b, aT1_g, aT1_be, 128, 7, A1);
    gin_bn(fs,  rps, srs, aSt,  aS_b,  aS_g,  aS_be,  256, 7, AS);

    // layer 2: shared extractor
    gin_bn(A0, rp0, sr0, extt, ext_b, ext_g, ext_be, 128, 6, o_h0);
    gin_bn(A1, rp1, sr1, extt, ext_b, ext_g, ext_be, 128, 6, o_h1);
    gin_bn(AS, rps, srs, extt, ext_b, ext_g, ext_be, 128, 6, o_hs);

    // layer 3: recon (Linear + ReLU), overwrite A0/A1/AS (dead)
    gin(o_h0, rp0, sr0, rT0t, rT0_b, o_f0, 64, 256);
    gin(o_h1, rp1, sr1, rT1t, rT1_b, o_f1, 64, 128);
}

// Round 4
// 2130.116 us; speedup vs baseline: 6.4680x; 1.2297x over previous
//
#include <hip/hip_runtime.h>

// ---------- weight transpose: W [Cout,Cin] -> Wt [Cin,Cout] ----------
__global__ void k_transpose(const float* __restrict__ W, float* __restrict__ Wt,
                            int Cin, int Cout) {
    int i = blockIdx.x * blockDim.x + threadIdx.x;
    if (i >= Cin * Cout) return;
    int k = i / Cout, c = i - k * Cout;
    Wt[i] = W[c * Cin + k];
}

// ---------- CSR build ----------
__global__ void k_hist(const int* __restrict__ dst, int* __restrict__ deg, int E) {
    int e = blockIdx.x * blockDim.x + threadIdx.x;
    if (e < E) atomicAdd(&deg[dst[e]], 1);
}

__global__ void k_scan(const int* __restrict__ deg, int* __restrict__ rowptr, int N) {
    __shared__ int tmp[1024];
    int tid = threadIdx.x;
    int chunk = (N + 1023) >> 10;
    int start = tid * chunk;
    int local = 0;
    for (int i = 0; i < chunk; ++i) {
        int idx = start + i;
        if (idx < N) local += deg[idx];
    }
    tmp[tid] = local;
    __syncthreads();
    for (int off = 1; off < 1024; off <<= 1) {
        int v = tmp[tid];
        if (tid >= off) v += tmp[tid - off];
        __syncthreads();
        tmp[tid] = v;
        __syncthreads();
    }
    int run = tmp[tid] - local;
    for (int i = 0; i < chunk; ++i) {
        int idx = start + i;
        if (idx < N) {
            rowptr[idx] = run;
            run += deg[idx];
        }
    }
    if (tid == 1023) rowptr[N] = tmp[1023];
}

__global__ void k_fill(const int* __restrict__ src, const int* __restrict__ dst,
                       int* __restrict__ cursor, int* __restrict__ srcs, int E) {
    int e = blockIdx.x * blockDim.x + threadIdx.x;
    if (e >= E) return;
    int pos = atomicAdd(&cursor[dst[e]], 1);
    srcs[pos] = src[e];
}

// ---------- dense linear: thread computes 4 nodes x 4 cols ----------
// optional fused BN+ReLU on the input read (stats: [C]=sum,[C..2C)=sumsq,[2C..3C)=scale,[3C..4C)=shift)
template <bool BN_IN, bool RELU_OUT>
__global__ void k_lin(const float* __restrict__ X, const float* __restrict__ stats,
                      const float* __restrict__ Wt, const float* __restrict__ bias,
                      float* __restrict__ Y, int N, int Cin, int Cout, int lgqc) {
    int idx = blockIdx.x * blockDim.x + threadIdx.x;
    int qc = 1 << lgqc;
    int cg = (idx & (qc - 1)) << 2;
    int n0 = (idx >> lgqc) << 2;
    if (n0 >= N) return;
    float4 b4 = *reinterpret_cast<const float4*>(bias + cg);
    float acc[4][4];
#pragma unroll
    for (int i = 0; i < 4; ++i) {
        acc[i][0] = b4.x; acc[i][1] = b4.y; acc[i][2] = b4.z; acc[i][3] = b4.w;
    }
    const float* x0 = X + (long)n0 * Cin;
#pragma unroll 4
    for (int k = 0; k < Cin; ++k) {
        float4 w = *reinterpret_cast<const float4*>(Wt + (long)k * Cout + cg);
        float xs[4];
#pragma unroll
        for (int i = 0; i < 4; ++i) xs[i] = x0[(long)i * Cin + k];
        if (BN_IN) {
            float sc = stats[2 * Cin + k], sh = stats[3 * Cin + k];
#pragma unroll
            for (int i = 0; i < 4; ++i) xs[i] = fmaxf(fmaf(xs[i], sc, sh), 0.f);
        }
#pragma unroll
        for (int i = 0; i < 4; ++i) {
            acc[i][0] = fmaf(xs[i], w.x, acc[i][0]);
            acc[i][1] = fmaf(xs[i], w.y, acc[i][1]);
            acc[i][2] = fmaf(xs[i], w.z, acc[i][2]);
            acc[i][3] = fmaf(xs[i], w.w, acc[i][3]);
        }
    }
#pragma unroll
    for (int i = 0; i < 4; ++i) {
        float4 o = make_float4(acc[i][0], acc[i][1], acc[i][2], acc[i][3]);
        if (RELU_OUT) {
            o.x = fmaxf(o.x, 0.f); o.y = fmaxf(o.y, 0.f);
            o.z = fmaxf(o.z, 0.f); o.w = fmaxf(o.w, 0.f);
        }
        *reinterpret_cast<float4*>(Y + (long)(n0 + i) * Cout + cg) = o;
    }
}

// ---------- aggregation: H[n] = Y[n] + sum_{e: dst==n} Y[src[e]] ----------
// one wave per node, lane-striped rows, 8-deep unroll for MLP
template <int NC>  // C = NC*64, NC in {1,2}
__global__ void k_agg(const float* __restrict__ Y, const int* __restrict__ rowptr,
                      const int* __restrict__ srcs, float* __restrict__ H, int N) {
    int l = threadIdx.x & 63;
    int n = (blockIdx.x << 2) + (threadIdx.x >> 6);
    if (n >= N) return;
    int p = rowptr[n], p1 = rowptr[n + 1];
    if constexpr (NC == 2) {
        const float2* Yb = reinterpret_cast<const float2*>(Y) + l;
        float2 a = Yb[(long)n << 6];
        float sx = a.x, sy = a.y;
        while (p + 8 <= p1) {
            int i0 = srcs[p], i1 = srcs[p + 1], i2 = srcs[p + 2], i3 = srcs[p + 3];
            int i4 = srcs[p + 4], i5 = srcs[p + 5], i6 = srcs[p + 6], i7 = srcs[p + 7];
            float2 r0 = Yb[(long)i0 << 6], r1 = Yb[(long)i1 << 6];
            float2 r2 = Yb[(long)i2 << 6], r3 = Yb[(long)i3 << 6];
            float2 r4 = Yb[(long)i4 << 6], r5 = Yb[(long)i5 << 6];
            float2 r6 = Yb[(long)i6 << 6], r7 = Yb[(long)i7 << 6];
            sx += ((r0.x + r1.x) + (r2.x + r3.x)) + ((r4.x + r5.x) + (r6.x + r7.x));
            sy += ((r0.y + r1.y) + (r2.y + r3.y)) + ((r4.y + r5.y) + (r6.y + r7.y));
            p += 8;
        }
        while (p < p1) {
            float2 r = Yb[(long)srcs[p] << 6];
            sx += r.x; sy += r.y; ++p;
        }
        float2 o = make_float2(sx, sy);
        (reinterpret_cast<float2*>(H) + l)[(long)n << 6] = o;
    } else {
        const float* Yb = Y + l;
        float s = Yb[(long)n << 6];
        while (p + 8 <= p1) {
            int i0 = srcs[p], i1 = srcs[p + 1], i2 = srcs[p + 2], i3 = srcs[p + 3];
            int i4 = srcs[p + 4], i5 = srcs[p + 5], i6 = srcs[p + 6], i7 = srcs[p + 7];
            float r0 = Yb[(long)i0 << 6], r1 = Yb[(long)i1 << 6];
            float r2 = Yb[(long)i2 << 6], r3 = Yb[(long)i3 << 6];
            float r4 = Yb[(long)i4 << 6], r5 = Yb[(long)i5 << 6];
            float r6 = Yb[(long)i6 << 6], r7 = Yb[(long)i7 << 6];
            s += ((r0 + r1) + (r2 + r3)) + ((r4 + r5) + (r6 + r7));
            p += 8;
        }
        while (p < p1) { s += Yb[(long)srcs[p] << 6]; ++p; }
        (H + l)[(long)n << 6] = s;
    }
}

// ---------- BN ----------
__global__ void k_bnstats(const float* __restrict__ h, float* __restrict__ stats,
                          int N, int C) {
    int tid = blockIdx.x * blockDim.x + threadIdx.x;
    int T = gridDim.x * blockDim.x;
    int c = tid & (C - 1);
    int chunk = tid / C;
    int nch = T / C;
    float s = 0.f, s2 = 0.f;
    for (int n = chunk; n < N; n += nch) {
        float v = h[(long)n * C + c];
        s += v;
        s2 = fmaf(v, v, s2);
    }
    unsafeAtomicAdd(&stats[c], s);
    unsafeAtomicAdd(&stats[C + c], s2);
}

__global__ void k_bnfin(float* __restrict__ stats, const float* __restrict__ g,
                        const float* __restrict__ beta, int C, float invN) {
    int c = threadIdx.x;
    if (c >= C) return;
    float m = stats[c] * invN;
    float v = stats[C + c] * invN - m * m;
    float sc = g[c] * rsqrtf(v + 1e-5f);
    stats[2 * C + c] = sc;
    stats[3 * C + c] = beta[c] - m * sc;
}

__global__ void k_bnapply(const float* __restrict__ h, const float* __restrict__ stats,
                          float* __restrict__ y, int N, int lgC) {
    int idx = blockIdx.x * blockDim.x + threadIdx.x;
    int C = 1 << lgC;
    int q = C >> 2;
    if (idx >= N * q) return;
    int n = idx >> (lgC - 2);
    int c4 = (idx & (q - 1)) << 2;
    const float4 hv = *reinterpret_cast<const float4*>(h + ((long)n << lgC) + c4);
    const float4 sc = *reinterpret_cast<const float4*>(stats + 2 * C + c4);
    const float4 sh = *reinterpret_cast<const float4*>(stats + 3 * C + c4);
    float4 o;
    o.x = fmaxf(fmaf(hv.x, sc.x, sh.x), 0.f);
    o.y = fmaxf(fmaf(hv.y, sc.y, sh.y), 0.f);
    o.z = fmaxf(fmaf(hv.z, sc.z, sh.z), 0.f);
    o.w = fmaxf(fmaf(hv.w, sc.w, sh.w), 0.f);
    *reinterpret_cast<float4*>(y + ((long)n << lgC) + c4) = o;
}

static inline int cdiv(long a, int b) { return (int)((a + b - 1) / b); }

extern "C" void kernel_launch(void* const* d_in, const int* in_sizes, int n_in,
                              void* d_out, int out_size, void* d_ws, size_t ws_size,
                              hipStream_t stream) {
    const float* ft0 = (const float*)d_in[0];
    const float* ft1 = (const float*)d_in[1];
    const float* fs  = (const float*)d_in[2];
    const int* et0 = (const int*)d_in[3];
    const int* et1 = (const int*)d_in[4];
    const int* es  = (const int*)d_in[5];
    const float* aT0_W = (const float*)d_in[6];
    const float* aT0_b = (const float*)d_in[7];
    const float* aT0_g = (const float*)d_in[8];
    const float* aT0_be = (const float*)d_in[9];
    const float* aT1_W = (const float*)d_in[10];
    const float* aT1_b = (const float*)d_in[11];
    const float* aT1_g = (const float*)d_in[12];
    const float* aT1_be = (const float*)d_in[13];
    const float* aS_W = (const float*)d_in[14];
    const float* aS_b = (const float*)d_in[15];
    const float* aS_g = (const float*)d_in[16];
    const float* aS_be = (const float*)d_in[17];
    const float* ext_W = (const float*)d_in[18];
    const float* ext_b = (const float*)d_in[19];
    const float* ext_g = (const float*)d_in[20];
    const float* ext_be = (const float*)d_in[21];
    const float* rT0_W = (const float*)d_in[22];
    const float* rT0_b = (const float*)d_in[23];
    const float* rT1_W = (const float*)d_in[24];
    const float* rT1_b = (const float*)d_in[25];

    const int N = in_sizes[0] / 256;
    const int E = in_sizes[3] / 2;

    float* out = (float*)d_out;
    float* o_hs = out;                      // [N,64]
    float* o_h0 = out + (long)N * 64;       // [N,64]
    float* o_h1 = out + (long)N * 128;      // [N,64]
    float* o_f0 = out + (long)N * 192;      // [N,256]
    float* o_f1 = out + (long)N * 448;      // [N,128]

    // L1 pre-BN activations live in the (not yet written) f0/f1 regions
    float* H0 = o_f0;                       // [N,128]
    float* H1 = o_f0 + (long)N * 128;       // [N,128]
    float* HS = o_f1;                       // [N,128]

    // workspace
    char* p = (char*)d_ws;
    float* Y  = (float*)p;     p += (size_t)N * 128 * 4;   // linear output (<=128 wide)
    float* h2 = (float*)p;     p += (size_t)N * 64 * 4;    // L2 pre-BN / L3 agg buffer
    int* rp0 = (int*)p;        p += (size_t)(N + 1) * 4;
    int* rp1 = (int*)p;        p += (size_t)(N + 1) * 4;
    int* rps = (int*)p;        p += (size_t)(N + 1) * 4;
    int* sr0 = (int*)p;        p += (size_t)E * 4;
    int* sr1 = (int*)p;        p += (size_t)E * 4;
    int* srs = (int*)p;        p += (size_t)E * 4;
    int* scratchN = (int*)p;   p += (size_t)N * 4;
    float* aT0t = (float*)p;   p += 256 * 128 * 4;
    float* aT1t = (float*)p;   p += 128 * 128 * 4;
    float* aSt  = (float*)p;   p += 256 * 128 * 4;
    float* extt = (float*)p;   p += 128 * 64 * 4;
    float* rT0t = (float*)p;   p += 64 * 256 * 4;
    float* rT1t = (float*)p;   p += 64 * 128 * 4;
    float* st0 = (float*)p;    p += 4 * 128 * 4;   // L1 stats per graph
    float* st1 = (float*)p;    p += 4 * 128 * 4;
    float* sts = (float*)p;    p += 4 * 128 * 4;
    float* st2 = (float*)p;    p += 4 * 64 * 4;    // L2 stats (reused per graph)

    // ---- CSR builds ----
    auto buildCSR = [&](const int* edge, int* rowptr, int* srcs) {
        const int* src = edge;
        const int* dst = edge + E;
        hipMemsetAsync(scratchN, 0, (size_t)N * 4, stream);
        k_hist<<<cdiv(E, 256), 256, 0, stream>>>(dst, scratchN, E);
        k_scan<<<1, 1024, 0, stream>>>(scratchN, rowptr, N);
        hipMemcpyAsync(scratchN, rowptr, (size_t)N * 4, hipMemcpyDeviceToDevice, stream);
        k_fill<<<cdiv(E, 256), 256, 0, stream>>>(src, dst, scratchN, srcs, E);
    };
    buildCSR(et0, rp0, sr0);
    buildCSR(et1, rp1, sr1);
    buildCSR(es, rps, srs);

    // ---- weight transposes ----
    auto T = [&](const float* W, float* Wt, int Cin, int Cout) {
        k_transpose<<<cdiv(Cin * Cout, 256), 256, 0, stream>>>(W, Wt, Cin, Cout);
    };
    T(aT0_W, aT0t, 256, 128);
    T(aT1_W, aT1t, 128, 128);
    T(aS_W, aSt, 256, 128);
    T(ext_W, extt, 128, 64);
    T(rT0_W, rT0t, 64, 256);
    T(rT1_W, rT1t, 64, 128);

    auto lgqc_of = [](int Cout) { return Cout == 256 ? 6 : Cout == 128 ? 5 : 4; };

    // ---- layer 1: Y = x @ Wt + b; H = Y + agg(Y); stats ----
    auto layer1 = [&](const float* x, const float* Wt, const float* b,
                      const float* g, const float* be, int Cin,
                      const int* rp, const int* sr, float* H, float* st) {
        int lgqc = lgqc_of(128);
        long thr = (long)(N / 4) * (1 << lgqc);
        k_lin<false, false><<<cdiv(thr, 256), 256, 0, stream>>>(x, nullptr, Wt, b, Y, N, Cin, 128, lgqc);
        k_agg<2><<<cdiv(N, 4), 256, 0, stream>>>(Y, rp, sr, H, N);
        hipMemsetAsync(st, 0, 2 * 128 * 4, stream);
        k_bnstats<<<1024, 256, 0, stream>>>(H, st, N, 128);
        k_bnfin<<<1, 128, 0, stream>>>(st, g, be, 128, 1.0f / N);
    };
    layer1(ft0, aT0t, aT0_b, aT0_g, aT0_be, 256, rp0, sr0, H0, st0);
    layer1(ft1, aT1t, aT1_b, aT1_g, aT1_be, 128, rp1, sr1, H1, st1);
    layer1(fs,  aSt,  aS_b,  aS_g,  aS_be,  256, rps, srs, HS, sts);

    // ---- layer 2: Y = bnrelu(H) @ extt + b; h2 = Y + agg(Y); bn-apply -> o_h ----
    auto layer2 = [&](const float* H, const float* st, const int* rp, const int* sr,
                      float* o_h) {
        int lgqc = lgqc_of(64);
        long thr = (long)(N / 4) * (1 << lgqc);
        k_lin<true, false><<<cdiv(thr, 256), 256, 0, stream>>>(H, st, extt, ext_b, Y, N, 128, 64, lgqc);
        k_agg<1><<<cdiv(N, 4), 256, 0, stream>>>(Y, rp, sr, h2, N);
        hipMemsetAsync(st2, 0, 2 * 64 * 4, stream);
        k_bnstats<<<1024, 256, 0, stream>>>(h2, st2, N, 64);
        k_bnfin<<<1, 64, 0, stream>>>(st2, ext_g, ext_be, 64, 1.0f / N);
        k_bnapply<<<cdiv((long)N * 16, 256), 256, 0, stream>>>(h2, st2, o_h, N, 6);
    };
    layer2(H0, st0, rp0, sr0, o_h0);
    layer2(H1, st1, rp1, sr1, o_h1);
    layer2(HS, sts, rps, srs, o_hs);

    // ---- layer 3: G = a + agg(a) in 64-dim; f = relu(G @ Wt + b) ----
    // (H0/H1/HS in the f0/f1 regions are dead now)
    {
        k_agg<1><<<cdiv(N, 4), 256, 0, stream>>>(o_h0, rp0, sr0, h2, N);
        long thr = (long)(N / 4) * 64;
        k_lin<false, true><<<cdiv(thr, 256), 256, 0, stream>>>(h2, nullptr, rT0t, rT0_b, o_f0, N, 64, 256, 6);
        k_agg<1><<<cdiv(N, 4), 256, 0, stream>>>(o_h1, rp1, sr1, h2, N);
        thr = (long)(N / 4) * 32;
        k_lin<false, true><<<cdiv(thr, 256), 256, 0, stream>>>(h2, nullptr, rT1t, rT1_b, o_f1, N, 64, 128, 5);
    }
}

// Round 5
// 1473.318 us; speedup vs baseline: 9.3513x; 1.4458x over previous
//
#include <hip/hip_runtime.h>

// ---------- weight transpose: W [Cout,Cin] -> Wt [Cin,Cout] ----------
__global__ void k_transpose(const float* __restrict__ W, float* __restrict__ Wt,
                            int Cin, int Cout) {
    int i = blockIdx.x * blockDim.x + threadIdx.x;
    if (i >= Cin * Cout) return;
    int k = i / Cout, c = i - k * Cout;
    Wt[i] = W[c * Cin + k];
}

// ---------- batched CSR build (3 graphs) ----------
__global__ void k_hist3(const int* __restrict__ e0, const int* __restrict__ e1,
                        const int* __restrict__ e2, int* __restrict__ deg, int E, int N) {
    int i = blockIdx.x * blockDim.x + threadIdx.x;
    if (i >= 3 * E) return;
    int g = i >= 2 * E ? 2 : (i >= E ? 1 : 0);
    const int* ep = g == 0 ? e0 : (g == 1 ? e1 : e2);
    int d = ep[E + i - g * E];
    atomicAdd(&deg[g * N + d], 1);
}

// blockIdx.x = graph. deg[g*N..] -> rowptr[g*(N+1)..]; also rewrites deg in place
// as the fill-cursor (exclusive offsets).
__global__ void k_scan3(int* __restrict__ deg, int* __restrict__ rowptr, int N) {
    __shared__ int tmp[1024];
    int g = blockIdx.x;
    int* dg = deg + (long)g * N;
    int* rp = rowptr + (long)g * (N + 1);
    int tid = threadIdx.x;
    int chunk = (N + 1023) >> 10;
    int start = tid * chunk;
    int local = 0;
    for (int i = 0; i < chunk; ++i) {
        int idx = start + i;
        if (idx < N) local += dg[idx];
    }
    tmp[tid] = local;
    __syncthreads();
    for (int off = 1; off < 1024; off <<= 1) {
        int v = tmp[tid];
        if (tid >= off) v += tmp[tid - off];
        __syncthreads();
        tmp[tid] = v;
        __syncthreads();
    }
    int run = tmp[tid] - local;
    for (int i = 0; i < chunk; ++i) {
        int idx = start + i;
        if (idx < N) {
            int dv = dg[idx];
            rp[idx] = run;
            dg[idx] = run;   // cursor copy
            run += dv;
        }
    }
    if (tid == 1023) rp[N] = tmp[1023];
}

__global__ void k_fill3(const int* __restrict__ e0, const int* __restrict__ e1,
                        const int* __restrict__ e2, int* __restrict__ cursor,
                        int* __restrict__ srcs, int E, int N) {
    int i = blockIdx.x * blockDim.x + threadIdx.x;
    if (i >= 3 * E) return;
    int g = i >= 2 * E ? 2 : (i >= E ? 1 : 0);
    const int* ep = g == 0 ? e0 : (g == 1 ? e1 : e2);
    int le = i - g * E;
    int d = ep[E + le], s = ep[le];
    int pos = atomicAdd(&cursor[g * N + d], 1);
    srcs[(long)g * E + pos] = s;
}

// ---------- dense linear: thread computes 8 nodes x 4 cols ----------
template <bool BN_IN, bool RELU_OUT>
__global__ void k_lin(const float* __restrict__ X, const float* __restrict__ stats,
                      const float* __restrict__ Wt, const float* __restrict__ bias,
                      float* __restrict__ Y, int N, int Cin, int Cout, int lgqc) {
    int idx = blockIdx.x * blockDim.x + threadIdx.x;
    int qc = 1 << lgqc;
    int cg = (idx & (qc - 1)) << 2;
    int n0 = (idx >> lgqc) << 3;
    if (n0 >= N) return;
    float4 b4 = *reinterpret_cast<const float4*>(bias + cg);
    float acc[8][4];
#pragma unroll
    for (int i = 0; i < 8; ++i) {
        acc[i][0] = b4.x; acc[i][1] = b4.y; acc[i][2] = b4.z; acc[i][3] = b4.w;
    }
    const float* x0 = X + (long)n0 * Cin;
#pragma unroll 4
    for (int k = 0; k < Cin; ++k) {
        float4 w = *reinterpret_cast<const float4*>(Wt + (long)k * Cout + cg);
        float xs[8];
#pragma unroll
        for (int i = 0; i < 8; ++i) xs[i] = x0[(long)i * Cin + k];
        if (BN_IN) {
            float sc = stats[2 * Cin + k], sh = stats[3 * Cin + k];
#pragma unroll
            for (int i = 0; i < 8; ++i) xs[i] = fmaxf(fmaf(xs[i], sc, sh), 0.f);
        }
#pragma unroll
        for (int i = 0; i < 8; ++i) {
            acc[i][0] = fmaf(xs[i], w.x, acc[i][0]);
            acc[i][1] = fmaf(xs[i], w.y, acc[i][1]);
            acc[i][2] = fmaf(xs[i], w.z, acc[i][2]);
            acc[i][3] = fmaf(xs[i], w.w, acc[i][3]);
        }
    }
#pragma unroll
    for (int i = 0; i < 8; ++i) {
        float4 o = make_float4(acc[i][0], acc[i][1], acc[i][2], acc[i][3]);
        if (RELU_OUT) {
            o.x = fmaxf(o.x, 0.f); o.y = fmaxf(o.y, 0.f);
            o.z = fmaxf(o.z, 0.f); o.w = fmaxf(o.w, 0.f);
        }
        *reinterpret_cast<float4*>(Y + (long)(n0 + i) * Cout + cg) = o;
    }
}

// ---------- aggregation: H[n] = Y[n] + sum_{e: dst==n} Y[src[e]] ----------
template <int NC>  // NC==2: C=128, 1 node/wave (float2/lane). NC==1: C=64, 2 nodes/wave.
__global__ void k_agg(const float* __restrict__ Y, const int* __restrict__ rowptr,
                      const int* __restrict__ srcs, float* __restrict__ H, int N) {
    if constexpr (NC == 2) {
        int l = threadIdx.x & 63;
        int n = (blockIdx.x << 2) + (threadIdx.x >> 6);
        if (n >= N) return;
        int p = rowptr[n], p1 = rowptr[n + 1];
        const float2* Yb = reinterpret_cast<const float2*>(Y) + l;
        float2 a = Yb[(long)n << 6];
        float sx = a.x, sy = a.y;
        while (p + 8 <= p1) {
            int i0 = srcs[p], i1 = srcs[p + 1], i2 = srcs[p + 2], i3 = srcs[p + 3];
            int i4 = srcs[p + 4], i5 = srcs[p + 5], i6 = srcs[p + 6], i7 = srcs[p + 7];
            float2 r0 = Yb[(long)i0 << 6], r1 = Yb[(long)i1 << 6];
            float2 r2 = Yb[(long)i2 << 6], r3 = Yb[(long)i3 << 6];
            float2 r4 = Yb[(long)i4 << 6], r5 = Yb[(long)i5 << 6];
            float2 r6 = Yb[(long)i6 << 6], r7 = Yb[(long)i7 << 6];
            sx += ((r0.x + r1.x) + (r2.x + r3.x)) + ((r4.x + r5.x) + (r6.x + r7.x));
            sy += ((r0.y + r1.y) + (r2.y + r3.y)) + ((r4.y + r5.y) + (r6.y + r7.y));
            p += 8;
        }
        while (p < p1) {
            float2 r = Yb[(long)srcs[p] << 6];
            sx += r.x; sy += r.y; ++p;
        }
        (reinterpret_cast<float2*>(H) + l)[(long)n << 6] = make_float2(sx, sy);
    } else {
        int l = threadIdx.x & 63;
        int ll = l & 31;
        int n = (blockIdx.x << 3) + ((threadIdx.x >> 6) << 1) + (l >> 5);
        if (n >= N) return;
        int p = rowptr[n], p1 = rowptr[n + 1];
        const float2* Yb = reinterpret_cast<const float2*>(Y) + ll;
        float2 a = Yb[(long)n << 5];
        float sx = a.x, sy = a.y;
        while (p + 8 <= p1) {
            int i0 = srcs[p], i1 = srcs[p + 1], i2 = srcs[p + 2], i3 = srcs[p + 3];
            int i4 = srcs[p + 4], i5 = srcs[p + 5], i6 = srcs[p + 6], i7 = srcs[p + 7];
            float2 r0 = Yb[(long)i0 << 5], r1 = Yb[(long)i1 << 5];
            float2 r2 = Yb[(long)i2 << 5], r3 = Yb[(long)i3 << 5];
            float2 r4 = Yb[(long)i4 << 5], r5 = Yb[(long)i5 << 5];
            float2 r6 = Yb[(long)i6 << 5], r7 = Yb[(long)i7 << 5];
            sx += ((r0.x + r1.x) + (r2.x + r3.x)) + ((r4.x + r5.x) + (r6.x + r7.x));
            sy += ((r0.y + r1.y) + (r2.y + r3.y)) + ((r4.y + r5.y) + (r6.y + r7.y));
            p += 8;
        }
        while (p < p1) {
            float2 r = Yb[(long)srcs[p] << 5];
            sx += r.x; sy += r.y; ++p;
        }
        (reinterpret_cast<float2*>(H) + ll)[(long)n << 5] = make_float2(sx, sy);
    }
}

// ---------- BN stats, two-stage deterministic ----------
// stage 1: 256 blocks; block b writes parts[b][0..C)=sum, parts[b][C..2C)=sumsq
template <int C>
__global__ void k_bnstats1(const float* __restrict__ h, float* __restrict__ parts, int N) {
    constexpr int RPB = 256 / C;
    constexpr int LGC = (C == 128) ? 7 : 6;
    __shared__ float ts[256], ts2[256];
    int tid = threadIdx.x;
    int c = tid & (C - 1);
    float s = 0.f, s2 = 0.f;
    for (int n = blockIdx.x * RPB + (tid >> LGC); n < N; n += 256 * RPB) {
        float v = h[((long)n << LGC) + c];
        s += v;
        s2 = fmaf(v, v, s2);
    }
    ts[tid] = s;
    ts2[tid] = s2;
    __syncthreads();
    if (tid < C) {
#pragma unroll
        for (int i = 1; i < RPB; ++i) {
            s += ts[tid + i * C];
            s2 += ts2[tid + i * C];
        }
        parts[blockIdx.x * 2 * C + tid] = s;
        parts[blockIdx.x * 2 * C + C + tid] = s2;
    }
}

// stage 2: one block of C threads; reduces 256 partials, emits scale/shift
template <int C>
__global__ void k_bnstats2(const float* __restrict__ parts, const float* __restrict__ g,
                           const float* __restrict__ beta, float* __restrict__ stats,
                           float invN) {
    int c = threadIdx.x;
    float s = 0.f, s2 = 0.f;
    for (int b = 0; b < 256; ++b) {
        s += parts[b * 2 * C + c];
        s2 += parts[b * 2 * C + C + c];
    }
    float m = s * invN;
    float v = s2 * invN - m * m;
    float sc = g[c] * rsqrtf(v + 1e-5f);
    stats[2 * C + c] = sc;
    stats[3 * C + c] = beta[c] - m * sc;
}

__global__ void k_bnapply(const float* __restrict__ h, const float* __restrict__ stats,
                          float* __restrict__ y, int N, int lgC) {
    int idx = blockIdx.x * blockDim.x + threadIdx.x;
    int C = 1 << lgC;
    int q = C >> 2;
    if (idx >= N * q) return;
    int n = idx >> (lgC - 2);
    int c4 = (idx & (q - 1)) << 2;
    const float4 hv = *reinterpret_cast<const float4*>(h + ((long)n << lgC) + c4);
    const float4 sc = *reinterpret_cast<const float4*>(stats + 2 * C + c4);
    const float4 sh = *reinterpret_cast<const float4*>(stats + 3 * C + c4);
    float4 o;
    o.x = fmaxf(fmaf(hv.x, sc.x, sh.x), 0.f);
    o.y = fmaxf(fmaf(hv.y, sc.y, sh.y), 0.f);
    o.z = fmaxf(fmaf(hv.z, sc.z, sh.z), 0.f);
    o.w = fmaxf(fmaf(hv.w, sc.w, sh.w), 0.f);
    *reinterpret_cast<float4*>(y + ((long)n << lgC) + c4) = o;
}

static inline int cdiv(long a, int b) { return (int)((a + b - 1) / b); }

extern "C" void kernel_launch(void* const* d_in, const int* in_sizes, int n_in,
                              void* d_out, int out_size, void* d_ws, size_t ws_size,
                              hipStream_t stream) {
    const float* ft0 = (const float*)d_in[0];
    const float* ft1 = (const float*)d_in[1];
    const float* fs  = (const float*)d_in[2];
    const int* et0 = (const int*)d_in[3];
    const int* et1 = (const int*)d_in[4];
    const int* es  = (const int*)d_in[5];
    const float* aT0_W = (const float*)d_in[6];
    const float* aT0_b = (const float*)d_in[7];
    const float* aT0_g = (const float*)d_in[8];
    const float* aT0_be = (const float*)d_in[9];
    const float* aT1_W = (const float*)d_in[10];
    const float* aT1_b = (const float*)d_in[11];
    const float* aT1_g = (const float*)d_in[12];
    const float* aT1_be = (const float*)d_in[13];
    const float* aS_W = (const float*)d_in[14];
    const float* aS_b = (const float*)d_in[15];
    const float* aS_g = (const float*)d_in[16];
    const float* aS_be = (const float*)d_in[17];
    const float* ext_W = (const float*)d_in[18];
    const float* ext_b = (const float*)d_in[19];
    const float* ext_g = (const float*)d_in[20];
    const float* ext_be = (const float*)d_in[21];
    const float* rT0_W = (const float*)d_in[22];
    const float* rT0_b = (const float*)d_in[23];
    const float* rT1_W = (const float*)d_in[24];
    const float* rT1_b = (const float*)d_in[25];

    const int N = in_sizes[0] / 256;
    const int E = in_sizes[3] / 2;

    float* out = (float*)d_out;
    float* o_hs = out;                      // [N,64]
    float* o_h0 = out + (long)N * 64;       // [N,64]
    float* o_h1 = out + (long)N * 128;      // [N,64]
    float* o_f0 = out + (long)N * 192;      // [N,256]
    float* o_f1 = out + (long)N * 448;      // [N,128]

    // L1 pre-BN activations live in the (not yet written) f0/f1 regions
    float* H0 = o_f0;                       // [N,128]
    float* H1 = o_f0 + (long)N * 128;       // [N,128]
    float* HS = o_f1;                       // [N,128]

    // workspace
    char* p = (char*)d_ws;
    float* Y  = (float*)p;     p += (size_t)N * 128 * 4;   // linear output (<=128 wide)
    float* h2 = (float*)p;     p += (size_t)N * 64 * 4;    // L2 pre-BN / L3 agg buffer
    int* rp   = (int*)p;       p += (size_t)3 * (N + 1) * 4;
    int* sr   = (int*)p;       p += (size_t)3 * E * 4;
    int* deg  = (int*)p;       p += (size_t)3 * N * 4;     // deg, then cursor
    float* aT0t = (float*)p;   p += 256 * 128 * 4;
    float* aT1t = (float*)p;   p += 128 * 128 * 4;
    float* aSt  = (float*)p;   p += 256 * 128 * 4;
    float* extt = (float*)p;   p += 128 * 64 * 4;
    float* rT0t = (float*)p;   p += 64 * 256 * 4;
    float* rT1t = (float*)p;   p += 64 * 128 * 4;
    float* st0 = (float*)p;    p += 4 * 128 * 4;
    float* st1 = (float*)p;    p += 4 * 128 * 4;
    float* sts = (float*)p;    p += 4 * 128 * 4;
    float* st2 = (float*)p;    p += 4 * 64 * 4;
    float* PARTS = (float*)p;  p += 256 * 256 * 4;

    int* rp0 = rp, *rp1 = rp + (N + 1), *rps = rp + 2 * (N + 1);
    int* sr0 = sr, *sr1 = sr + E, *srs = sr + 2 * E;

    // ---- batched CSR build ----
    hipMemsetAsync(deg, 0, (size_t)3 * N * 4, stream);
    k_hist3<<<cdiv((long)3 * E, 256), 256, 0, stream>>>(et0, et1, es, deg, E, N);
    k_scan3<<<3, 1024, 0, stream>>>(deg, rp, N);
    k_fill3<<<cdiv((long)3 * E, 256), 256, 0, stream>>>(et0, et1, es, deg, sr, E, N);

    // ---- weight transposes ----
    auto T = [&](const float* W, float* Wt, int Cin, int Cout) {
        k_transpose<<<cdiv(Cin * Cout, 256), 256, 0, stream>>>(W, Wt, Cin, Cout);
    };
    T(aT0_W, aT0t, 256, 128);
    T(aT1_W, aT1t, 128, 128);
    T(aS_W, aSt, 256, 128);
    T(ext_W, extt, 128, 64);
    T(rT0_W, rT0t, 64, 256);
    T(rT1_W, rT1t, 64, 128);

    // ---- layer 1: Y = x @ Wt + b; H = Y + agg(Y); stats ----
    auto layer1 = [&](const float* x, const float* Wt, const float* b,
                      const float* g, const float* be, int Cin,
                      const int* rpg, const int* srg, float* H, float* st) {
        long thr = (long)(N / 8) * 32;
        k_lin<false, false><<<cdiv(thr, 256), 256, 0, stream>>>(x, nullptr, Wt, b, Y, N, Cin, 128, 5);
        k_agg<2><<<cdiv(N, 4), 256, 0, stream>>>(Y, rpg, srg, H, N);
        k_bnstats1<128><<<256, 256, 0, stream>>>(H, PARTS, N);
        k_bnstats2<128><<<1, 128, 0, stream>>>(PARTS, g, be, st, 1.0f / N);
    };
    layer1(ft0, aT0t, aT0_b, aT0_g, aT0_be, 256, rp0, sr0, H0, st0);
    layer1(ft1, aT1t, aT1_b, aT1_g, aT1_be, 128, rp1, sr1, H1, st1);
    layer1(fs,  aSt,  aS_b,  aS_g,  aS_be,  256, rps, srs, HS, sts);

    // ---- layer 2: Y = bnrelu(H) @ extt + b; h2 = Y + agg(Y); bn-apply -> o_h ----
    auto layer2 = [&](const float* H, const float* st, const int* rpg, const int* srg,
                      float* o_h) {
        long thr = (long)(N / 8) * 16;
        k_lin<true, false><<<cdiv(thr, 256), 256, 0, stream>>>(H, st, extt, ext_b, Y, N, 128, 64, 4);
        k_agg<1><<<cdiv(N, 8), 256, 0, stream>>>(Y, rpg, srg, h2, N);
        k_bnstats1<64><<<256, 256, 0, stream>>>(h2, PARTS, N);
        k_bnstats2<64><<<1, 64, 0, stream>>>(PARTS, ext_g, ext_be, st2, 1.0f / N);
        k_bnapply<<<cdiv((long)N * 16, 256), 256, 0, stream>>>(h2, st2, o_h, N, 6);
    };
    layer2(H0, st0, rp0, sr0, o_h0);
    layer2(H1, st1, rp1, sr1, o_h1);
    layer2(HS, sts, rps, srs, o_hs);

    // ---- layer 3: G = a + agg(a) in 64-dim; f = relu(G @ Wt + b) ----
    {
        k_agg<1><<<cdiv(N, 8), 256, 0, stream>>>(o_h0, rp0, sr0, h2, N);
        long thr = (long)(N / 8) * 64;
        k_lin<false, true><<<cdiv(thr, 256), 256, 0, stream>>>(h2, nullptr, rT0t, rT0_b, o_f0, N, 64, 256, 6);
        k_agg<1><<<cdiv(N, 8), 256, 0, stream>>>(o_h1, rp1, sr1, h2, N);
        thr = (long)(N / 8) * 32;
        k_lin<false, true><<<cdiv(thr, 256), 256, 0, stream>>>(h2, nullptr, rT1t, rT1_b, o_f1, N, 64, 128, 5);
    }
}

// Round 6
// 1321.938 us; speedup vs baseline: 10.4222x; 1.1145x over previous
//
#include <hip/hip_runtime.h>
#include <hip/hip_bf16.h>

__device__ __forceinline__ float bf2f(unsigned short u) {
    return __uint_as_float(((unsigned)u) << 16);
}
__device__ __forceinline__ unsigned short f2bf(float f) {
    __hip_bfloat16 h = __float2bfloat16(f);   // RNE
    return *reinterpret_cast<unsigned short*>(&h);
}

// ---------- weight transpose: W [Cout,Cin] -> Wt [Cin,Cout] ----------
__global__ void k_transpose(const float* __restrict__ W, float* __restrict__ Wt,
                            int Cin, int Cout) {
    int i = blockIdx.x * blockDim.x + threadIdx.x;
    if (i >= Cin * Cout) return;
    int k = i / Cout, c = i - k * Cout;
    Wt[i] = W[c * Cin + k];
}

// ---------- batched CSR build (3 graphs) ----------
__global__ void k_hist3(const int* __restrict__ e0, const int* __restrict__ e1,
                        const int* __restrict__ e2, int* __restrict__ deg, int E, int N) {
    int i = blockIdx.x * blockDim.x + threadIdx.x;
    if (i >= 3 * E) return;
    int g = i >= 2 * E ? 2 : (i >= E ? 1 : 0);
    const int* ep = g == 0 ? e0 : (g == 1 ? e1 : e2);
    int d = ep[E + i - g * E];
    atomicAdd(&deg[g * N + d], 1);
}

__global__ void k_scan3(int* __restrict__ deg, int* __restrict__ rowptr, int N) {
    __shared__ int tmp[1024];
    int g = blockIdx.x;
    int* dg = deg + (long)g * N;
    int* rp = rowptr + (long)g * (N + 1);
    int tid = threadIdx.x;
    int chunk = (N + 1023) >> 10;
    int start = tid * chunk;
    int local = 0;
    for (int i = 0; i < chunk; ++i) {
        int idx = start + i;
        if (idx < N) local += dg[idx];
    }
    tmp[tid] = local;
    __syncthreads();
    for (int off = 1; off < 1024; off <<= 1) {
        int v = tmp[tid];
        if (tid >= off) v += tmp[tid - off];
        __syncthreads();
        tmp[tid] = v;
        __syncthreads();
    }
    int run = tmp[tid] - local;
    for (int i = 0; i < chunk; ++i) {
        int idx = start + i;
        if (idx < N) {
            int dv = dg[idx];
            rp[idx] = run;
            dg[idx] = run;   // cursor copy
            run += dv;
        }
    }
    if (tid == 1023) rp[N] = tmp[1023];
}

__global__ void k_fill3(const int* __restrict__ e0, const int* __restrict__ e1,
                        const int* __restrict__ e2, int* __restrict__ cursor,
                        int* __restrict__ srcs, int E, int N) {
    int i = blockIdx.x * blockDim.x + threadIdx.x;
    if (i >= 3 * E) return;
    int g = i >= 2 * E ? 2 : (i >= E ? 1 : 0);
    const int* ep = g == 0 ? e0 : (g == 1 ? e1 : e2);
    int le = i - g * E;
    int d = ep[E + le], s = ep[le];
    int pos = atomicAdd(&cursor[g * N + d], 1);
    srcs[(long)g * E + pos] = s;
}

// ---------- dense linear: thread computes 8 nodes x 4 cols ----------
template <bool BN_IN, bool RELU_OUT, bool BF16_OUT>
__global__ void k_lin(const float* __restrict__ X, const float* __restrict__ stats,
                      const float* __restrict__ Wt, const float* __restrict__ bias,
                      void* __restrict__ Yv, int N, int Cin, int Cout, int lgqc) {
    int idx = blockIdx.x * blockDim.x + threadIdx.x;
    int qc = 1 << lgqc;
    int cg = (idx & (qc - 1)) << 2;
    int n0 = (idx >> lgqc) << 3;
    if (n0 >= N) return;
    float4 b4 = *reinterpret_cast<const float4*>(bias + cg);
    float acc[8][4];
#pragma unroll
    for (int i = 0; i < 8; ++i) {
        acc[i][0] = b4.x; acc[i][1] = b4.y; acc[i][2] = b4.z; acc[i][3] = b4.w;
    }
    const float* x0 = X + (long)n0 * Cin;
#pragma unroll 4
    for (int k = 0; k < Cin; ++k) {
        float4 w = *reinterpret_cast<const float4*>(Wt + (long)k * Cout + cg);
        float xs[8];
#pragma unroll
        for (int i = 0; i < 8; ++i) xs[i] = x0[(long)i * Cin + k];
        if (BN_IN) {
            float sc = stats[2 * Cin + k], sh = stats[3 * Cin + k];
#pragma unroll
            for (int i = 0; i < 8; ++i) xs[i] = fmaxf(fmaf(xs[i], sc, sh), 0.f);
        }
#pragma unroll
        for (int i = 0; i < 8; ++i) {
            acc[i][0] = fmaf(xs[i], w.x, acc[i][0]);
            acc[i][1] = fmaf(xs[i], w.y, acc[i][1]);
            acc[i][2] = fmaf(xs[i], w.z, acc[i][2]);
            acc[i][3] = fmaf(xs[i], w.w, acc[i][3]);
        }
    }
#pragma unroll
    for (int i = 0; i < 8; ++i) {
        float o0 = acc[i][0], o1 = acc[i][1], o2 = acc[i][2], o3 = acc[i][3];
        if (RELU_OUT) {
            o0 = fmaxf(o0, 0.f); o1 = fmaxf(o1, 0.f);
            o2 = fmaxf(o2, 0.f); o3 = fmaxf(o3, 0.f);
        }
        if (BF16_OUT) {
            ushort4 o = make_ushort4(f2bf(o0), f2bf(o1), f2bf(o2), f2bf(o3));
            *reinterpret_cast<ushort4*>((unsigned short*)Yv + (long)(n0 + i) * Cout + cg) = o;
        } else {
            *reinterpret_cast<float4*>((float*)Yv + (long)(n0 + i) * Cout + cg) =
                make_float4(o0, o1, o2, o3);
        }
    }
}

// ---------- aggregation from bf16 rows: H[n] = Y[n] + sum_{e} Y[src[e]] (fp32 out) ----------
// 32-lane row slicing, 2 nodes per wave, 8 nodes per block.
template <int CH>  // CH in {128, 64}
__global__ void k_aggb(const unsigned short* __restrict__ Y, const int* __restrict__ rowptr,
                       const int* __restrict__ srcs, float* __restrict__ H, int N) {
    int l = threadIdx.x & 63;
    int ll = l & 31;
    int n = (blockIdx.x << 3) + ((threadIdx.x >> 6) << 1) + (l >> 5);
    if (n >= N) return;
    int p = rowptr[n], p1 = rowptr[n + 1];
    if constexpr (CH == 128) {
        const ushort4* Yp = reinterpret_cast<const ushort4*>(Y) + ll;   // 4 ch/lane, 32/row
        ushort4 a = Yp[(long)n << 5];
        float s0 = bf2f(a.x), s1 = bf2f(a.y), s2 = bf2f(a.z), s3 = bf2f(a.w);
        while (p + 8 <= p1) {
            ushort4 r[8];
#pragma unroll
            for (int j = 0; j < 8; ++j) r[j] = Yp[(long)srcs[p + j] << 5];
#pragma unroll
            for (int j = 0; j < 8; ++j) {
                s0 += bf2f(r[j].x); s1 += bf2f(r[j].y);
                s2 += bf2f(r[j].z); s3 += bf2f(r[j].w);
            }
            p += 8;
        }
        while (p < p1) {
            ushort4 r = Yp[(long)srcs[p] << 5];
            s0 += bf2f(r.x); s1 += bf2f(r.y); s2 += bf2f(r.z); s3 += bf2f(r.w);
            ++p;
        }
        *reinterpret_cast<float4*>(H + ((long)n << 7) + (ll << 2)) = make_float4(s0, s1, s2, s3);
    } else {
        const unsigned* Yp = reinterpret_cast<const unsigned*>(Y) + ll;  // 2 ch/lane, 32/row
        unsigned a = Yp[(long)n << 5];
        float s0 = bf2f((unsigned short)a), s1 = bf2f((unsigned short)(a >> 16));
        while (p + 8 <= p1) {
            unsigned r[8];
#pragma unroll
            for (int j = 0; j < 8; ++j) r[j] = Yp[(long)srcs[p + j] << 5];
#pragma unroll
            for (int j = 0; j < 8; ++j) {
                s0 += bf2f((unsigned short)r[j]);
                s1 += bf2f((unsigned short)(r[j] >> 16));
            }
            p += 8;
        }
        while (p < p1) {
            unsigned r = Yp[(long)srcs[p] << 5];
            s0 += bf2f((unsigned short)r);
            s1 += bf2f((unsigned short)(r >> 16));
            ++p;
        }
        *reinterpret_cast<float2*>(H + ((long)n << 6) + (ll << 1)) = make_float2(s0, s1);
    }
}

// ---------- BN stats, two-stage deterministic ----------
template <int C>
__global__ void k_bnstats1(const float* __restrict__ h, float* __restrict__ parts, int N) {
    constexpr int RPB = 256 / C;
    constexpr int LGC = (C == 128) ? 7 : 6;
    __shared__ float ts[256], ts2[256];
    int tid = threadIdx.x;
    int c = tid & (C - 1);
    float s = 0.f, s2 = 0.f;
    for (int n = blockIdx.x * RPB + (tid >> LGC); n < N; n += 256 * RPB) {
        float v = h[((long)n << LGC) + c];
        s += v;
        s2 = fmaf(v, v, s2);
    }
    ts[tid] = s;
    ts2[tid] = s2;
    __syncthreads();
    if (tid < C) {
#pragma unroll
        for (int i = 1; i < RPB; ++i) {
            s += ts[tid + i * C];
            s2 += ts2[tid + i * C];
        }
        parts[blockIdx.x * 2 * C + tid] = s;
        parts[blockIdx.x * 2 * C + C + tid] = s2;
    }
}

template <int C>
__global__ void k_bnstats2(const float* __restrict__ parts, const float* __restrict__ g,
                           const float* __restrict__ beta, float* __restrict__ stats,
                           float invN) {
    int c = threadIdx.x;
    float s = 0.f, s2 = 0.f;
    for (int b = 0; b < 256; ++b) {
        s += parts[b * 2 * C + c];
        s2 += parts[b * 2 * C + C + c];
    }
    float m = s * invN;
    float v = s2 * invN - m * m;
    float sc = g[c] * rsqrtf(v + 1e-5f);
    stats[2 * C + c] = sc;
    stats[3 * C + c] = beta[c] - m * sc;
}

// y = relu(h*scale + shift); optionally also emit bf16 copy
template <bool EMIT_B>
__global__ void k_bnapply(const float* __restrict__ h, const float* __restrict__ stats,
                          float* __restrict__ y, unsigned short* __restrict__ yb,
                          int N, int lgC) {
    int idx = blockIdx.x * blockDim.x + threadIdx.x;
    int C = 1 << lgC;
    int q = C >> 2;
    if (idx >= N * q) return;
    int n = idx >> (lgC - 2);
    int c4 = (idx & (q - 1)) << 2;
    const float4 hv = *reinterpret_cast<const float4*>(h + ((long)n << lgC) + c4);
    const float4 sc = *reinterpret_cast<const float4*>(stats + 2 * C + c4);
    const float4 sh = *reinterpret_cast<const float4*>(stats + 3 * C + c4);
    float4 o;
    o.x = fmaxf(fmaf(hv.x, sc.x, sh.x), 0.f);
    o.y = fmaxf(fmaf(hv.y, sc.y, sh.y), 0.f);
    o.z = fmaxf(fmaf(hv.z, sc.z, sh.z), 0.f);
    o.w = fmaxf(fmaf(hv.w, sc.w, sh.w), 0.f);
    *reinterpret_cast<float4*>(y + ((long)n << lgC) + c4) = o;
    if (EMIT_B) {
        ushort4 ob = make_ushort4(f2bf(o.x), f2bf(o.y), f2bf(o.z), f2bf(o.w));
        *reinterpret_cast<ushort4*>(yb + ((long)n << lgC) + c4) = ob;
    }
}

static inline int cdiv(long a, int b) { return (int)((a + b - 1) / b); }

extern "C" void kernel_launch(void* const* d_in, const int* in_sizes, int n_in,
                              void* d_out, int out_size, void* d_ws, size_t ws_size,
                              hipStream_t stream) {
    const float* ft0 = (const float*)d_in[0];
    const float* ft1 = (const float*)d_in[1];
    const float* fs  = (const float*)d_in[2];
    const int* et0 = (const int*)d_in[3];
    const int* et1 = (const int*)d_in[4];
    const int* es  = (const int*)d_in[5];
    const float* aT0_W = (const float*)d_in[6];
    const float* aT0_b = (const float*)d_in[7];
    const float* aT0_g = (const float*)d_in[8];
    const float* aT0_be = (const float*)d_in[9];
    const float* aT1_W = (const float*)d_in[10];
    const float* aT1_b = (const float*)d_in[11];
    const float* aT1_g = (const float*)d_in[12];
    const float* aT1_be = (const float*)d_in[13];
    const float* aS_W = (const float*)d_in[14];
    const float* aS_b = (const float*)d_in[15];
    const float* aS_g = (const float*)d_in[16];
    const float* aS_be = (const float*)d_in[17];
    const float* ext_W = (const float*)d_in[18];
    const float* ext_b = (const float*)d_in[19];
    const float* ext_g = (const float*)d_in[20];
    const float* ext_be = (const float*)d_in[21];
    const float* rT0_W = (const float*)d_in[22];
    const float* rT0_b = (const float*)d_in[23];
    const float* rT1_W = (const float*)d_in[24];
    const float* rT1_b = (const float*)d_in[25];

    const int N = in_sizes[0] / 256;
    const int E = in_sizes[3] / 2;

    float* out = (float*)d_out;
    float* o_hs = out;                      // [N,64]
    float* o_h0 = out + (long)N * 64;       // [N,64]
    float* o_h1 = out + (long)N * 128;      // [N,64]
    float* o_f0 = out + (long)N * 192;      // [N,256]
    float* o_f1 = out + (long)N * 448;      // [N,128]

    // L1 pre-BN activations live in the (not yet written) f0/f1 regions
    float* H0 = o_f0;                       // [N,128]
    float* H1 = o_f0 + (long)N * 128;       // [N,128]
    float* HS = o_f1;                       // [N,128]

    // workspace
    char* p = (char*)d_ws;
    unsigned short* Yb = (unsigned short*)p; p += (size_t)N * 128 * 2;  // bf16 linear out
    float* h2 = (float*)p;     p += (size_t)N * 64 * 4;                 // L2 pre-BN / L3 agg
    unsigned short* ob0 = (unsigned short*)p; p += (size_t)N * 64 * 2;  // bf16 o_h0
    unsigned short* ob1 = (unsigned short*)p; p += (size_t)N * 64 * 2;  // bf16 o_h1
    int* rp   = (int*)p;       p += (size_t)3 * (N + 1) * 4;
    int* sr   = (int*)p;       p += (size_t)3 * E * 4;
    int* deg  = (int*)p;       p += (size_t)3 * N * 4;
    float* aT0t = (float*)p;   p += 256 * 128 * 4;
    float* aT1t = (float*)p;   p += 128 * 128 * 4;
    float* aSt  = (float*)p;   p += 256 * 128 * 4;
    float* extt = (float*)p;   p += 128 * 64 * 4;
    float* rT0t = (float*)p;   p += 64 * 256 * 4;
    float* rT1t = (float*)p;   p += 64 * 128 * 4;
    float* st0 = (float*)p;    p += 4 * 128 * 4;
    float* st1 = (float*)p;    p += 4 * 128 * 4;
    float* sts = (float*)p;    p += 4 * 128 * 4;
    float* st2 = (float*)p;    p += 4 * 64 * 4;
    float* PARTS = (float*)p;  p += 256 * 256 * 4;

    int* rp0 = rp, *rp1 = rp + (N + 1), *rps = rp + 2 * (N + 1);
    int* sr0 = sr, *sr1 = sr + E, *srs = sr + 2 * E;

    // ---- batched CSR build ----
    hipMemsetAsync(deg, 0, (size_t)3 * N * 4, stream);
    k_hist3<<<cdiv((long)3 * E, 256), 256, 0, stream>>>(et0, et1, es, deg, E, N);
    k_scan3<<<3, 1024, 0, stream>>>(deg, rp, N);
    k_fill3<<<cdiv((long)3 * E, 256), 256, 0, stream>>>(et0, et1, es, deg, sr, E, N);

    // ---- weight transposes ----
    auto T = [&](const float* W, float* Wt, int Cin, int Cout) {
        k_transpose<<<cdiv(Cin * Cout, 256), 256, 0, stream>>>(W, Wt, Cin, Cout);
    };
    T(aT0_W, aT0t, 256, 128);
    T(aT1_W, aT1t, 128, 128);
    T(aS_W, aSt, 256, 128);
    T(ext_W, extt, 128, 64);
    T(rT0_W, rT0t, 64, 256);
    T(rT1_W, rT1t, 64, 128);

    // ---- layer 1: Yb = bf16(x @ Wt + b); H = Yb[n] + agg(Yb); stats ----
    auto layer1 = [&](const float* x, const float* Wt, const float* b,
                      const float* g, const float* be, int Cin,
                      const int* rpg, const int* srg, float* H, float* st) {
        long thr = (long)(N / 8) * 32;
        k_lin<false, false, true><<<cdiv(thr, 256), 256, 0, stream>>>(x, nullptr, Wt, b, Yb, N, Cin, 128, 5);
        k_aggb<128><<<cdiv(N, 8), 256, 0, stream>>>(Yb, rpg, srg, H, N);
        k_bnstats1<128><<<256, 256, 0, stream>>>(H, PARTS, N);
        k_bnstats2<128><<<1, 128, 0, stream>>>(PARTS, g, be, st, 1.0f / N);
    };
    layer1(ft0, aT0t, aT0_b, aT0_g, aT0_be, 256, rp0, sr0, H0, st0);
    layer1(ft1, aT1t, aT1_b, aT1_g, aT1_be, 128, rp1, sr1, H1, st1);
    layer1(fs,  aSt,  aS_b,  aS_g,  aS_be,  256, rps, srs, HS, sts);

    // ---- layer 2: Yb = bf16(bnrelu(H) @ extt + b); h2 = agg(Yb); bn-apply ----
    auto layer2 = [&](const float* H, const float* st, const int* rpg, const int* srg,
                      float* o_h, unsigned short* o_hb) {
        long thr = (long)(N / 8) * 16;
        k_lin<true, false, true><<<cdiv(thr, 256), 256, 0, stream>>>(H, st, extt, ext_b, Yb, N, 128, 64, 4);
        k_aggb<64><<<cdiv(N, 8), 256, 0, stream>>>(Yb, rpg, srg, h2, N);
        k_bnstats1<64><<<256, 256, 0, stream>>>(h2, PARTS, N);
        k_bnstats2<64><<<1, 64, 0, stream>>>(PARTS, ext_g, ext_be, st2, 1.0f / N);
        if (o_hb)
            k_bnapply<true><<<cdiv((long)N * 16, 256), 256, 0, stream>>>(h2, st2, o_h, o_hb, N, 6);
        else
            k_bnapply<false><<<cdiv((long)N * 16, 256), 256, 0, stream>>>(h2, st2, o_h, nullptr, N, 6);
    };
    layer2(H0, st0, rp0, sr0, o_h0, ob0);
    layer2(H1, st1, rp1, sr1, o_h1, ob1);
    layer2(HS, sts, rps, srs, o_hs, nullptr);

    // ---- layer 3: G = agg(bf16 o_h); f = relu(G @ Wt + b) ----
    {
        k_aggb<64><<<cdiv(N, 8), 256, 0, stream>>>(ob0, rp0, sr0, h2, N);
        long thr = (long)(N / 8) * 64;
        k_lin<false, true, false><<<cdiv(thr, 256), 256, 0, stream>>>(h2, nullptr, rT0t, rT0_b, o_f0, N, 64, 256, 6);
        k_aggb<64><<<cdiv(N, 8), 256, 0, stream>>>(ob1, rp1, sr1, h2, N);
        thr = (long)(N / 8) * 32;
        k_lin<false, true, false><<<cdiv(thr, 256), 256, 0, stream>>>(h2, nullptr, rT1t, rT1_b, o_f1, N, 64, 128, 5);
    }
}

// Round 7
// 998.634 us; speedup vs baseline: 13.7963x; 1.3237x over previous
//
#include <hip/hip_runtime.h>
#include <hip/hip_bf16.h>

#define CPE 8192   // edges per partition chunk

__device__ __forceinline__ float bf2f(unsigned short u) {
    return __uint_as_float(((unsigned)u) << 16);
}
__device__ __forceinline__ unsigned short f2bf(float f) {
    __hip_bfloat16 h = __float2bfloat16(f);   // RNE
    return *reinterpret_cast<unsigned short*>(&h);
}

// ---------- weight transpose: W [Cout,Cin] -> Wt [Cin,Cout] ----------
__global__ void k_transpose(const float* __restrict__ W, float* __restrict__ Wt,
                            int Cin, int Cout) {
    int i = blockIdx.x * blockDim.x + threadIdx.x;
    if (i >= Cin * Cout) return;
    int k = i / Cout, c = i - k * Cout;
    Wt[i] = W[c * Cin + k];
}

// ================= CSR build via coarse-bucket counting sort =================
// record u32 = ((dst & 255) << 16) | src   (requires N <= 65536)

// P1: per (g,chunk): LDS hist over NB buckets -> cnt[g][b][chunk]
__global__ void k_p1(const int* __restrict__ e0, const int* __restrict__ e1,
                     const int* __restrict__ e2, int* __restrict__ cnt,
                     int E, int nC, int NB) {
    __shared__ int h[256];
    int g = blockIdx.x / nC, c = blockIdx.x - g * nC;
    const int* dst = (g == 0 ? e0 : g == 1 ? e1 : e2) + E;
    for (int b = threadIdx.x; b < NB; b += 256) h[b] = 0;
    __syncthreads();
    int lo = c * CPE, hi = min(E, lo + CPE);
    for (int e = lo + threadIdx.x; e < hi; e += 256)
        atomicAdd(&h[dst[e] >> 8], 1);
    __syncthreads();
    for (int b = threadIdx.x; b < NB; b += 256)
        cnt[((long)g * NB + b) * nC + c] = h[b];
}

// P2a: tot[g][b] = sum_c cnt[g][b][c]
__global__ void k_p2a(const int* __restrict__ cnt, int* __restrict__ tot, int nC) {
    __shared__ int s[256];
    long gb = blockIdx.x;
    const int* row = cnt + gb * nC;
    int v = 0;
    for (int c = threadIdx.x; c < nC; c += 256) v += row[c];
    s[threadIdx.x] = v;
    __syncthreads();
    for (int o = 128; o > 0; o >>= 1) {
        if (threadIdx.x < o) s[threadIdx.x] += s[threadIdx.x + o];
        __syncthreads();
    }
    if (threadIdx.x == 0) tot[gb] = s[0];
}

// P2b: per graph, exclusive scan NB totals -> baseE[g][b]; sentinels
__global__ void k_p2b(const int* __restrict__ tot, int* __restrict__ baseE,
                      int* __restrict__ rowptr, int E, int N, int NB) {
    __shared__ int s[256];
    int g = blockIdx.x, t = threadIdx.x;
    int v = (t < NB) ? tot[g * NB + t] : 0;
    s[t] = v;
    __syncthreads();
    for (int o = 1; o < 256; o <<= 1) {
        int a = (t >= o) ? s[t - o] : 0;
        __syncthreads();
        s[t] += a;
        __syncthreads();
    }
    if (t < NB) baseE[g * (NB + 1) + t] = s[t] - v;
    if (t == 0) {
        baseE[g * (NB + 1) + NB] = E;
        rowptr[(long)g * (N + 1) + N] = E;
    }
}

// P2c: ofs[g][b][c] = baseE[g][b] + exclusive_prefix_c(cnt[g][b][c])  (nC <= 256)
__global__ void k_p2c(const int* __restrict__ cnt, const int* __restrict__ baseE,
                      int* __restrict__ ofs, int nC, int NB) {
    __shared__ int s[256];
    long gb = blockIdx.x;
    int g = (int)(gb / NB), b = (int)(gb - (long)g * NB);
    int t = threadIdx.x;
    int v = (t < nC) ? cnt[gb * nC + t] : 0;
    s[t] = v;
    __syncthreads();
    for (int o = 1; o < 256; o <<= 1) {
        int a = (t >= o) ? s[t - o] : 0;
        __syncthreads();
        s[t] += a;
        __syncthreads();
    }
    if (t < nC) ofs[gb * nC + t] = baseE[g * (NB + 1) + b] + s[t] - v;
}

// P3: partition scatter -> part[g][pos] = record (bucket-grouped, chunk-sequential)
__global__ void k_p3(const int* __restrict__ e0, const int* __restrict__ e1,
                     const int* __restrict__ e2, const int* __restrict__ ofs,
                     unsigned* __restrict__ part, int E, int nC, int NB) {
    __shared__ int lbase[256];
    __shared__ int lcur[256];
    int g = blockIdx.x / nC, c = blockIdx.x - g * nC;
    const int* eg = (g == 0 ? e0 : g == 1 ? e1 : e2);
    const int* src = eg;
    const int* dst = eg + E;
    for (int b = threadIdx.x; b < NB; b += 256) {
        lbase[b] = ofs[((long)g * NB + b) * nC + c];
        lcur[b] = 0;
    }
    __syncthreads();
    int lo = c * CPE, hi = min(E, lo + CPE);
    unsigned* pg = part + (long)g * E;
    for (int e = lo + threadIdx.x; e < hi; e += 256) {
        int d = dst[e];
        int b = d >> 8;
        int pos = lbase[b] + atomicAdd(&lcur[b], 1);
        pg[pos] = ((unsigned)(d & 255) << 16) | (unsigned)src[e];
    }
}

// P4: per (g,bucket): rowptr for 256 local nodes + srcs fill within 16KB window
__global__ void k_p4(const unsigned* __restrict__ part, const int* __restrict__ baseE,
                     int* __restrict__ rowptr, int* __restrict__ srcs,
                     int E, int N, int NB) {
    __shared__ int h[256];
    __shared__ int s[256];
    __shared__ int cur[256];
    int g = blockIdx.x / NB, b = blockIdx.x - g * NB;
    int n0 = b << 8;
    int nn = min(256, N - n0);
    int lo = baseE[g * (NB + 1) + b], hi = baseE[g * (NB + 1) + b + 1];
    int t = threadIdx.x;
    h[t] = 0;
    __syncthreads();
    const unsigned* pg = part + (long)g * E;
    for (int i = lo + t; i < hi; i += 256)
        atomicAdd(&h[pg[i] >> 16], 1);
    __syncthreads();
    int v = h[t];
    s[t] = v;
    __syncthreads();
    for (int o = 1; o < 256; o <<= 1) {
        int a = (t >= o) ? s[t - o] : 0;
        __syncthreads();
        s[t] += a;
        __syncthreads();
    }
    int excl = lo + s[t] - v;
    if (t < nn) rowptr[(long)g * (N + 1) + n0 + t] = excl;
    cur[t] = excl;
    __syncthreads();
    int* sg = srcs + (long)g * E;
    for (int i = lo + t; i < hi; i += 256) {
        unsigned r = pg[i];
        int pos = atomicAdd(&cur[r >> 16], 1);
        sg[pos] = (int)(r & 0xFFFFu);
    }
}

// ---------- dense linear: thread computes 8 nodes x 4 cols ----------
template <bool BN_IN, bool RELU_OUT, bool BF16_OUT>
__global__ void k_lin(const float* __restrict__ X, const float* __restrict__ stats,
                      const float* __restrict__ Wt, const float* __restrict__ bias,
                      void* __restrict__ Yv, int N, int Cin, int Cout, int lgqc) {
    int idx = blockIdx.x * blockDim.x + threadIdx.x;
    int qc = 1 << lgqc;
    int cg = (idx & (qc - 1)) << 2;
    int n0 = (idx >> lgqc) << 3;
    if (n0 >= N) return;
    float4 b4 = *reinterpret_cast<const float4*>(bias + cg);
    float acc[8][4];
#pragma unroll
    for (int i = 0; i < 8; ++i) {
        acc[i][0] = b4.x; acc[i][1] = b4.y; acc[i][2] = b4.z; acc[i][3] = b4.w;
    }
    const float* x0 = X + (long)n0 * Cin;
#pragma unroll 4
    for (int k = 0; k < Cin; ++k) {
        float4 w = *reinterpret_cast<const float4*>(Wt + (long)k * Cout + cg);
        float xs[8];
#pragma unroll
        for (int i = 0; i < 8; ++i) xs[i] = x0[(long)i * Cin + k];
        if (BN_IN) {
            float sc = stats[2 * Cin + k], sh = stats[3 * Cin + k];
#pragma unroll
            for (int i = 0; i < 8; ++i) xs[i] = fmaxf(fmaf(xs[i], sc, sh), 0.f);
        }
#pragma unroll
        for (int i = 0; i < 8; ++i) {
            acc[i][0] = fmaf(xs[i], w.x, acc[i][0]);
            acc[i][1] = fmaf(xs[i], w.y, acc[i][1]);
            acc[i][2] = fmaf(xs[i], w.z, acc[i][2]);
            acc[i][3] = fmaf(xs[i], w.w, acc[i][3]);
        }
    }
#pragma unroll
    for (int i = 0; i < 8; ++i) {
        float o0 = acc[i][0], o1 = acc[i][1], o2 = acc[i][2], o3 = acc[i][3];
        if (RELU_OUT) {
            o0 = fmaxf(o0, 0.f); o1 = fmaxf(o1, 0.f);
            o2 = fmaxf(o2, 0.f); o3 = fmaxf(o3, 0.f);
        }
        if (BF16_OUT) {
            ushort4 o = make_ushort4(f2bf(o0), f2bf(o1), f2bf(o2), f2bf(o3));
            *reinterpret_cast<ushort4*>((unsigned short*)Yv + (long)(n0 + i) * Cout + cg) = o;
        } else {
            *reinterpret_cast<float4*>((float*)Yv + (long)(n0 + i) * Cout + cg) =
                make_float4(o0, o1, o2, o3);
        }
    }
}

// ---------- aggregation from bf16 rows: H[n] = Y[n] + sum_{e} Y[src[e]] (fp32 out) ----------
template <int CH>  // CH in {128, 64}
__global__ void k_aggb(const unsigned short* __restrict__ Y, const int* __restrict__ rowptr,
                       const int* __restrict__ srcs, float* __restrict__ H, int N) {
    int l = threadIdx.x & 63;
    int ll = l & 31;
    int n = (blockIdx.x << 3) + ((threadIdx.x >> 6) << 1) + (l >> 5);
    if (n >= N) return;
    int p = rowptr[n], p1 = rowptr[n + 1];
    if constexpr (CH == 128) {
        const ushort4* Yp = reinterpret_cast<const ushort4*>(Y) + ll;
        ushort4 a = Yp[(long)n << 5];
        float s0 = bf2f(a.x), s1 = bf2f(a.y), s2 = bf2f(a.z), s3 = bf2f(a.w);
        while (p + 8 <= p1) {
            ushort4 r[8];
#pragma unroll
            for (int j = 0; j < 8; ++j) r[j] = Yp[(long)srcs[p + j] << 5];
#pragma unroll
            for (int j = 0; j < 8; ++j) {
                s0 += bf2f(r[j].x); s1 += bf2f(r[j].y);
                s2 += bf2f(r[j].z); s3 += bf2f(r[j].w);
            }
            p += 8;
        }
        while (p < p1) {
            ushort4 r = Yp[(long)srcs[p] << 5];
            s0 += bf2f(r.x); s1 += bf2f(r.y); s2 += bf2f(r.z); s3 += bf2f(r.w);
            ++p;
        }
        *reinterpret_cast<float4*>(H + ((long)n << 7) + (ll << 2)) = make_float4(s0, s1, s2, s3);
    } else {
        const unsigned* Yp = reinterpret_cast<const unsigned*>(Y) + ll;
        unsigned a = Yp[(long)n << 5];
        float s0 = bf2f((unsigned short)a), s1 = bf2f((unsigned short)(a >> 16));
        while (p + 8 <= p1) {
            unsigned r[8];
#pragma unroll
            for (int j = 0; j < 8; ++j) r[j] = Yp[(long)srcs[p + j] << 5];
#pragma unroll
            for (int j = 0; j < 8; ++j) {
                s0 += bf2f((unsigned short)r[j]);
                s1 += bf2f((unsigned short)(r[j] >> 16));
            }
            p += 8;
        }
        while (p < p1) {
            unsigned r = Yp[(long)srcs[p] << 5];
            s0 += bf2f((unsigned short)r);
            s1 += bf2f((unsigned short)(r >> 16));
            ++p;
        }
        *reinterpret_cast<float2*>(H + ((long)n << 6) + (ll << 1)) = make_float2(s0, s1);
    }
}

// ---------- BN stats, two-stage deterministic ----------
template <int C>
__global__ void k_bnstats1(const float* __restrict__ h, float* __restrict__ parts, int N) {
    constexpr int RPB = 256 / C;
    constexpr int LGC = (C == 128) ? 7 : 6;
    __shared__ float ts[256], ts2[256];
    int tid = threadIdx.x;
    int c = tid & (C - 1);
    float s = 0.f, s2 = 0.f;
    for (int n = blockIdx.x * RPB + (tid >> LGC); n < N; n += 256 * RPB) {
        float v = h[((long)n << LGC) + c];
        s += v;
        s2 = fmaf(v, v, s2);
    }
    ts[tid] = s;
    ts2[tid] = s2;
    __syncthreads();
    if (tid < C) {
#pragma unroll
        for (int i = 1; i < RPB; ++i) {
            s += ts[tid + i * C];
            s2 += ts2[tid + i * C];
        }
        parts[blockIdx.x * 2 * C + tid] = s;
        parts[blockIdx.x * 2 * C + C + tid] = s2;
    }
}

template <int C>
__global__ void k_bnstats2(const float* __restrict__ parts, const float* __restrict__ g,
                           const float* __restrict__ beta, float* __restrict__ stats,
                           float invN) {
    int c = threadIdx.x;
    float s = 0.f, s2 = 0.f;
    for (int b = 0; b < 256; ++b) {
        s += parts[b * 2 * C + c];
        s2 += parts[b * 2 * C + C + c];
    }
    float m = s * invN;
    float v = s2 * invN - m * m;
    float sc = g[c] * rsqrtf(v + 1e-5f);
    stats[2 * C + c] = sc;
    stats[3 * C + c] = beta[c] - m * sc;
}

// y = relu(h*scale + shift); optionally also emit bf16 copy
template <bool EMIT_B>
__global__ void k_bnapply(const float* __restrict__ h, const float* __restrict__ stats,
                          float* __restrict__ y, unsigned short* __restrict__ yb,
                          int N, int lgC) {
    int idx = blockIdx.x * blockDim.x + threadIdx.x;
    int C = 1 << lgC;
    int q = C >> 2;
    if (idx >= N * q) return;
    int n = idx >> (lgC - 2);
    int c4 = (idx & (q - 1)) << 2;
    const float4 hv = *reinterpret_cast<const float4*>(h + ((long)n << lgC) + c4);
    const float4 sc = *reinterpret_cast<const float4*>(stats + 2 * C + c4);
    const float4 sh = *reinterpret_cast<const float4*>(stats + 3 * C + c4);
    float4 o;
    o.x = fmaxf(fmaf(hv.x, sc.x, sh.x), 0.f);
    o.y = fmaxf(fmaf(hv.y, sc.y, sh.y), 0.f);
    o.z = fmaxf(fmaf(hv.z, sc.z, sh.z), 0.f);
    o.w = fmaxf(fmaf(hv.w, sc.w, sh.w), 0.f);
    *reinterpret_cast<float4*>(y + ((long)n << lgC) + c4) = o;
    if (EMIT_B) {
        ushort4 ob = make_ushort4(f2bf(o.x), f2bf(o.y), f2bf(o.z), f2bf(o.w));
        *reinterpret_cast<ushort4*>(yb + ((long)n << lgC) + c4) = ob;
    }
}

static inline int cdiv(long a, int b) { return (int)((a + b - 1) / b); }

extern "C" void kernel_launch(void* const* d_in, const int* in_sizes, int n_in,
                              void* d_out, int out_size, void* d_ws, size_t ws_size,
                              hipStream_t stream) {
    const float* ft0 = (const float*)d_in[0];
    const float* ft1 = (const float*)d_in[1];
    const float* fs  = (const float*)d_in[2];
    const int* et0 = (const int*)d_in[3];
    const int* et1 = (const int*)d_in[4];
    const int* es  = (const int*)d_in[5];
    const float* aT0_W = (const float*)d_in[6];
    const float* aT0_b = (const float*)d_in[7];
    const float* aT0_g = (const float*)d_in[8];
    const float* aT0_be = (const float*)d_in[9];
    const float* aT1_W = (const float*)d_in[10];
    const float* aT1_b = (const float*)d_in[11];
    const float* aT1_g = (const float*)d_in[12];
    const float* aT1_be = (const float*)d_in[13];
    const float* aS_W = (const float*)d_in[14];
    const float* aS_b = (const float*)d_in[15];
    const float* aS_g = (const float*)d_in[16];
    const float* aS_be = (const float*)d_in[17];
    const float* ext_W = (const float*)d_in[18];
    const float* ext_b = (const float*)d_in[19];
    const float* ext_g = (const float*)d_in[20];
    const float* ext_be = (const float*)d_in[21];
    const float* rT0_W = (const float*)d_in[22];
    const float* rT0_b = (const float*)d_in[23];
    const float* rT1_W = (const float*)d_in[24];
    const float* rT1_b = (const float*)d_in[25];

    const int N = in_sizes[0] / 256;
    const int E = in_sizes[3] / 2;
    const int NB = cdiv(N, 256);        // coarse buckets (N <= 65536)
    const int nC = cdiv(E, CPE);        // chunks per graph (<= 256)

    float* out = (float*)d_out;
    float* o_hs = out;                      // [N,64]
    float* o_h0 = out + (long)N * 64;       // [N,64]
    float* o_h1 = out + (long)N * 128;      // [N,64]
    float* o_f0 = out + (long)N * 192;      // [N,256]
    float* o_f1 = out + (long)N * 448;      // [N,128]

    // L1 pre-BN activations live in the (not yet written) f0/f1 regions
    float* H0 = o_f0;                       // [N,128]
    float* H1 = o_f0 + (long)N * 128;       // [N,128]
    float* HS = o_f1;                       // [N,128]

    // workspace
    char* p = (char*)d_ws;
    unsigned short* Yb = (unsigned short*)p; p += (size_t)N * 128 * 2;
    float* h2 = (float*)p;     p += (size_t)N * 64 * 4;
    unsigned short* ob0 = (unsigned short*)p; p += (size_t)N * 64 * 2;
    unsigned short* ob1 = (unsigned short*)p; p += (size_t)N * 64 * 2;
    int* rp   = (int*)p;       p += (size_t)3 * (N + 1) * 4;
    int* sr   = (int*)p;       p += (size_t)3 * E * 4;
    unsigned* part = (unsigned*)p; p += (size_t)3 * E * 4;
    int* cnt  = (int*)p;       p += (size_t)3 * NB * nC * 4;
    int* ofs  = (int*)p;       p += (size_t)3 * NB * nC * 4;
    int* tot  = (int*)p;       p += (size_t)3 * NB * 4;
    int* baseE = (int*)p;      p += (size_t)3 * (NB + 1) * 4;
    float* aT0t = (float*)p;   p += 256 * 128 * 4;
    float* aT1t = (float*)p;   p += 128 * 128 * 4;
    float* aSt  = (float*)p;   p += 256 * 128 * 4;
    float* extt = (float*)p;   p += 128 * 64 * 4;
    float* rT0t = (float*)p;   p += 64 * 256 * 4;
    float* rT1t = (float*)p;   p += 64 * 128 * 4;
    float* st0 = (float*)p;    p += 4 * 128 * 4;
    float* st1 = (float*)p;    p += 4 * 128 * 4;
    float* sts = (float*)p;    p += 4 * 128 * 4;
    float* st2 = (float*)p;    p += 4 * 64 * 4;
    float* PARTS = (float*)p;  p += 256 * 256 * 4;

    int* rp0 = rp, *rp1 = rp + (N + 1), *rps = rp + 2 * (N + 1);
    int* sr0 = sr, *sr1 = sr + E, *srs = sr + 2 * E;

    // ---- CSR build (counting sort by coarse bucket) ----
    k_p1<<<3 * nC, 256, 0, stream>>>(et0, et1, es, cnt, E, nC, NB);
    k_p2a<<<3 * NB, 256, 0, stream>>>(cnt, tot, nC);
    k_p2b<<<3, 256, 0, stream>>>(tot, baseE, rp, E, N, NB);
    k_p2c<<<3 * NB, 256, 0, stream>>>(cnt, baseE, ofs, nC, NB);
    k_p3<<<3 * nC, 256, 0, stream>>>(et0, et1, es, ofs, part, E, nC, NB);
    k_p4<<<3 * NB, 256, 0, stream>>>(part, baseE, rp, sr, E, N, NB);

    // ---- weight transposes ----
    auto T = [&](const float* W, float* Wt, int Cin, int Cout) {
        k_transpose<<<cdiv(Cin * Cout, 256), 256, 0, stream>>>(W, Wt, Cin, Cout);
    };
    T(aT0_W, aT0t, 256, 128);
    T(aT1_W, aT1t, 128, 128);
    T(aS_W, aSt, 256, 128);
    T(ext_W, extt, 128, 64);
    T(rT0_W, rT0t, 64, 256);
    T(rT1_W, rT1t, 64, 128);

    // ---- layer 1: Yb = bf16(x @ Wt + b); H = Yb[n] + agg(Yb); stats ----
    auto layer1 = [&](const float* x, const float* Wt, const float* b,
                      const float* g, const float* be, int Cin,
                      const int* rpg, const int* srg, float* H, float* st) {
        long thr = (long)(N / 8) * 32;
        k_lin<false, false, true><<<cdiv(thr, 256), 256, 0, stream>>>(x, nullptr, Wt, b, Yb, N, Cin, 128, 5);
        k_aggb<128><<<cdiv(N, 8), 256, 0, stream>>>(Yb, rpg, srg, H, N);
        k_bnstats1<128><<<256, 256, 0, stream>>>(H, PARTS, N);
        k_bnstats2<128><<<1, 128, 0, stream>>>(PARTS, g, be, st, 1.0f / N);
    };
    layer1(ft0, aT0t, aT0_b, aT0_g, aT0_be, 256, rp0, sr0, H0, st0);
    layer1(ft1, aT1t, aT1_b, aT1_g, aT1_be, 128, rp1, sr1, H1, st1);
    layer1(fs,  aSt,  aS_b,  aS_g,  aS_be,  256, rps, srs, HS, sts);

    // ---- layer 2: Yb = bf16(bnrelu(H) @ extt + b); h2 = agg(Yb); bn-apply ----
    auto layer2 = [&](const float* H, const float* st, const int* rpg, const int* srg,
                      float* o_h, unsigned short* o_hb) {
        long thr = (long)(N / 8) * 16;
        k_lin<true, false, true><<<cdiv(thr, 256), 256, 0, stream>>>(H, st, extt, ext_b, Yb, N, 128, 64, 4);
        k_aggb<64><<<cdiv(N, 8), 256, 0, stream>>>(Yb, rpg, srg, h2, N);
        k_bnstats1<64><<<256, 256, 0, stream>>>(h2, PARTS, N);
        k_bnstats2<64><<<1, 64, 0, stream>>>(PARTS, ext_g, ext_be, st2, 1.0f / N);
        if (o_hb)
            k_bnapply<true><<<cdiv((long)N * 16, 256), 256, 0, stream>>>(h2, st2, o_h, o_hb, N, 6);
        else
            k_bnapply<false><<<cdiv((long)N * 16, 256), 256, 0, stream>>>(h2, st2, o_h, nullptr, N, 6);
    };
    layer2(H0, st0, rp0, sr0, o_h0, ob0);
    layer2(H1, st1, rp1, sr1, o_h1, ob1);
    layer2(HS, sts, rps, srs, o_hs, nullptr);

    // ---- layer 3: G = agg(bf16 o_h); f = relu(G @ Wt + b) ----
    {
        k_aggb<64><<<cdiv(N, 8), 256, 0, stream>>>(ob0, rp0, sr0, h2, N);
        long thr = (long)(N / 8) * 64;
        k_lin<false, true, false><<<cdiv(thr, 256), 256, 0, stream>>>(h2, nullptr, rT0t, rT0_b, o_f0, N, 64, 256, 6);
        k_aggb<64><<<cdiv(N, 8), 256, 0, stream>>>(ob1, rp1, sr1, h2, N);
        thr = (long)(N / 8) * 32;
        k_lin<false, true, false><<<cdiv(thr, 256), 256, 0, stream>>>(h2, nullptr, rT1t, rT1_b, o_f1, N, 64, 128, 5);
    }
}

// Round 8
// 720.343 us; speedup vs baseline: 19.1263x; 1.3863x over previous
//
#include <hip/hip_runtime.h>
#include <hip/hip_bf16.h>

#define CPE 8192   // edges per partition chunk

typedef short short8 __attribute__((ext_vector_type(8)));
typedef float f32x4 __attribute__((ext_vector_type(4)));

__device__ __forceinline__ float bf2f(unsigned short u) {
    return __uint_as_float(((unsigned)u) << 16);
}
__device__ __forceinline__ unsigned short f2bf(float f) {
    __hip_bfloat16 h = __float2bfloat16(f);   // RNE
    return *reinterpret_cast<unsigned short*>(&h);
}

// ---------- weight convert: fp32 [Cout*Cin] -> bf16 same layout ----------
__global__ void k_wcvt(const float* __restrict__ W, unsigned short* __restrict__ Wb, int sz) {
    int i = blockIdx.x * blockDim.x + threadIdx.x;
    if (i < sz) Wb[i] = f2bf(W[i]);
}

// ================= CSR build via coarse-bucket counting sort =================
// record u32 = ((dst & 255) << 16) | src   (requires N <= 65536)

__global__ void k_p1(const int* __restrict__ e0, const int* __restrict__ e1,
                     const int* __restrict__ e2, int* __restrict__ cnt,
                     int E, int nC, int NB) {
    __shared__ int h[256];
    int g = blockIdx.x / nC, c = blockIdx.x - g * nC;
    const int* dst = (g == 0 ? e0 : g == 1 ? e1 : e2) + E;
    for (int b = threadIdx.x; b < NB; b += 256) h[b] = 0;
    __syncthreads();
    int lo = c * CPE, hi = min(E, lo + CPE);
    for (int e = lo + threadIdx.x; e < hi; e += 256)
        atomicAdd(&h[dst[e] >> 8], 1);
    __syncthreads();
    for (int b = threadIdx.x; b < NB; b += 256)
        cnt[((long)g * NB + b) * nC + c] = h[b];
}

__global__ void k_p2a(const int* __restrict__ cnt, int* __restrict__ tot, int nC) {
    __shared__ int s[256];
    long gb = blockIdx.x;
    const int* row = cnt + gb * nC;
    int v = 0;
    for (int c = threadIdx.x; c < nC; c += 256) v += row[c];
    s[threadIdx.x] = v;
    __syncthreads();
    for (int o = 128; o > 0; o >>= 1) {
        if (threadIdx.x < o) s[threadIdx.x] += s[threadIdx.x + o];
        __syncthreads();
    }
    if (threadIdx.x == 0) tot[gb] = s[0];
}

__global__ void k_p2b(const int* __restrict__ tot, int* __restrict__ baseE,
                      int* __restrict__ rowptr, int E, int N, int NB) {
    __shared__ int s[256];
    int g = blockIdx.x, t = threadIdx.x;
    int v = (t < NB) ? tot[g * NB + t] : 0;
    s[t] = v;
    __syncthreads();
    for (int o = 1; o < 256; o <<= 1) {
        int a = (t >= o) ? s[t - o] : 0;
        __syncthreads();
        s[t] += a;
        __syncthreads();
    }
    if (t < NB) baseE[g * (NB + 1) + t] = s[t] - v;
    if (t == 0) {
        baseE[g * (NB + 1) + NB] = E;
        rowptr[(long)g * (N + 1) + N] = E;
    }
}

__global__ void k_p2c(const int* __restrict__ cnt, const int* __restrict__ baseE,
                      int* __restrict__ ofs, int nC, int NB) {
    __shared__ int s[256];
    long gb = blockIdx.x;
    int g = (int)(gb / NB), b = (int)(gb - (long)g * NB);
    int t = threadIdx.x;
    int v = (t < nC) ? cnt[gb * nC + t] : 0;
    s[t] = v;
    __syncthreads();
    for (int o = 1; o < 256; o <<= 1) {
        int a = (t >= o) ? s[t - o] : 0;
        __syncthreads();
        s[t] += a;
        __syncthreads();
    }
    if (t < nC) ofs[gb * nC + t] = baseE[g * (NB + 1) + b] + s[t] - v;
}

__global__ void k_p3(const int* __restrict__ e0, const int* __restrict__ e1,
                     const int* __restrict__ e2, const int* __restrict__ ofs,
                     unsigned* __restrict__ part, int E, int nC, int NB) {
    __shared__ int lbase[256];
    __shared__ int lcur[256];
    int g = blockIdx.x / nC, c = blockIdx.x - g * nC;
    const int* eg = (g == 0 ? e0 : g == 1 ? e1 : e2);
    const int* src = eg;
    const int* dst = eg + E;
    for (int b = threadIdx.x; b < NB; b += 256) {
        lbase[b] = ofs[((long)g * NB + b) * nC + c];
        lcur[b] = 0;
    }
    __syncthreads();
    int lo = c * CPE, hi = min(E, lo + CPE);
    unsigned* pg = part + (long)g * E;
    for (int e = lo + threadIdx.x; e < hi; e += 256) {
        int d = dst[e];
        int b = d >> 8;
        int pos = lbase[b] + atomicAdd(&lcur[b], 1);
        pg[pos] = ((unsigned)(d & 255) << 16) | (unsigned)src[e];
    }
}

__global__ void k_p4(const unsigned* __restrict__ part, const int* __restrict__ baseE,
                     int* __restrict__ rowptr, int* __restrict__ srcs,
                     int E, int N, int NB) {
    __shared__ int h[256];
    __shared__ int s[256];
    __shared__ int cur[256];
    int g = blockIdx.x / NB, b = blockIdx.x - g * NB;
    int n0 = b << 8;
    int nn = min(256, N - n0);
    int lo = baseE[g * (NB + 1) + b], hi = baseE[g * (NB + 1) + b + 1];
    int t = threadIdx.x;
    h[t] = 0;
    __syncthreads();
    const unsigned* pg = part + (long)g * E;
    for (int i = lo + t; i < hi; i += 256)
        atomicAdd(&h[pg[i] >> 16], 1);
    __syncthreads();
    int v = h[t];
    s[t] = v;
    __syncthreads();
    for (int o = 1; o < 256; o <<= 1) {
        int a = (t >= o) ? s[t - o] : 0;
        __syncthreads();
        s[t] += a;
        __syncthreads();
    }
    int excl = lo + s[t] - v;
    if (t < nn) rowptr[(long)g * (N + 1) + n0 + t] = excl;
    cur[t] = excl;
    __syncthreads();
    int* sg = srcs + (long)g * E;
    for (int i = lo + t; i < hi; i += 256) {
        unsigned r = pg[i];
        int pos = atomicAdd(&cur[r >> 16], 1);
        sg[pos] = (int)(r & 0xFFFFu);
    }
}

// ---------- MFMA GEMM: Y[N,COUT] = act(X[N,CIN] @ W^T + b) ----------
// W kept in original [COUT,CIN] layout, bf16. One wave: 16 rows x 64 cols.
// A-frag: row = lane&15, k = (lane>>4)*8 + j (fp32 load, bf16 pack in-reg)
// B-frag: col = lane&15, k = (lane>>4)*8 + j (16B bf16 load, k-contiguous)
// D: row = (lane>>4)*4 + r, col = lane&15   [m89/m91-verified]
template <int CIN, int CG, bool BN_IN, bool RELU_OUT, bool BF16_OUT>
__global__ __launch_bounds__(256) void k_gemm(const float* __restrict__ X,
                                              const float* __restrict__ stats,
                                              const unsigned short* __restrict__ Wb,
                                              const float* __restrict__ bias,
                                              void* __restrict__ Yv, int MT) {
    constexpr int COUT = CG * 64;
    constexpr int SH = (CG == 1) ? 0 : (CG == 2) ? 1 : 2;
    int w = blockIdx.x * 4 + (threadIdx.x >> 6);
    int l = threadIdx.x & 63;
    int mt = w >> SH;
    if (mt >= MT) return;
    int cg = w & (CG - 1);
    int lm = l & 15, lh = l >> 4;
    int kb = lh * 8;

    const float* xr = X + (long)(mt * 16 + lm) * CIN + kb;
    const unsigned short* wp[4];
#pragma unroll
    for (int t = 0; t < 4; ++t)
        wp[t] = Wb + (long)(cg * 64 + t * 16 + lm) * CIN + kb;
    const float* scp = nullptr;
    const float* shp = nullptr;
    if (BN_IN) {
        scp = stats + 2 * CIN + kb;
        shp = stats + 3 * CIN + kb;
    }

    f32x4 acc[4];
#pragma unroll
    for (int t = 0; t < 4; ++t) acc[t] = (f32x4){0.f, 0.f, 0.f, 0.f};

    for (int k0 = 0; k0 < CIN; k0 += 32) {
        float4 x0 = *reinterpret_cast<const float4*>(xr);
        float4 x1 = *reinterpret_cast<const float4*>(xr + 4);
        if (BN_IN) {
            float4 s0 = *reinterpret_cast<const float4*>(scp);
            float4 s1 = *reinterpret_cast<const float4*>(scp + 4);
            float4 h0 = *reinterpret_cast<const float4*>(shp);
            float4 h1 = *reinterpret_cast<const float4*>(shp + 4);
            x0.x = fmaxf(fmaf(x0.x, s0.x, h0.x), 0.f);
            x0.y = fmaxf(fmaf(x0.y, s0.y, h0.y), 0.f);
            x0.z = fmaxf(fmaf(x0.z, s0.z, h0.z), 0.f);
            x0.w = fmaxf(fmaf(x0.w, s0.w, h0.w), 0.f);
            x1.x = fmaxf(fmaf(x1.x, s1.x, h1.x), 0.f);
            x1.y = fmaxf(fmaf(x1.y, s1.y, h1.y), 0.f);
            x1.z = fmaxf(fmaf(x1.z, s1.z, h1.z), 0.f);
            x1.w = fmaxf(fmaf(x1.w, s1.w, h1.w), 0.f);
            scp += 32;
            shp += 32;
        }
        short8 a;
        a[0] = (short)f2bf(x0.x); a[1] = (short)f2bf(x0.y);
        a[2] = (short)f2bf(x0.z); a[3] = (short)f2bf(x0.w);
        a[4] = (short)f2bf(x1.x); a[5] = (short)f2bf(x1.y);
        a[6] = (short)f2bf(x1.z); a[7] = (short)f2bf(x1.w);
#pragma unroll
        for (int t = 0; t < 4; ++t) {
            short8 b = *reinterpret_cast<const short8*>(wp[t]);
            acc[t] = __builtin_amdgcn_mfma_f32_16x16x32_bf16(a, b, acc[t], 0, 0, 0);
            wp[t] += 32;
        }
        xr += 32;
    }

    int nb = mt * 16 + lh * 4;
#pragma unroll
    for (int t = 0; t < 4; ++t) {
        int col = cg * 64 + t * 16 + lm;
        float bi = bias[col];
#pragma unroll
        for (int r = 0; r < 4; ++r) {
            float v = acc[t][r] + bi;
            if (RELU_OUT) v = fmaxf(v, 0.f);
            if (BF16_OUT)
                ((unsigned short*)Yv)[(long)(nb + r) * COUT + col] = f2bf(v);
            else
                ((float*)Yv)[(long)(nb + r) * COUT + col] = v;
        }
    }
}

// ---------- aggregation from bf16 rows: H[n] = Y[n] + sum_{e} Y[src[e]] (fp32 out) ----------
template <int CH>  // CH in {128, 64}
__global__ void k_aggb(const unsigned short* __restrict__ Y, const int* __restrict__ rowptr,
                       const int* __restrict__ srcs, float* __restrict__ H, int N) {
    int l = threadIdx.x & 63;
    int ll = l & 31;
    int n = (blockIdx.x << 3) + ((threadIdx.x >> 6) << 1) + (l >> 5);
    if (n >= N) return;
    int p = rowptr[n], p1 = rowptr[n + 1];
    if constexpr (CH == 128) {
        const ushort4* Yp = reinterpret_cast<const ushort4*>(Y) + ll;
        ushort4 a = Yp[(long)n << 5];
        float s0 = bf2f(a.x), s1 = bf2f(a.y), s2 = bf2f(a.z), s3 = bf2f(a.w);
        while (p + 8 <= p1) {
            ushort4 r[8];
#pragma unroll
            for (int j = 0; j < 8; ++j) r[j] = Yp[(long)srcs[p + j] << 5];
#pragma unroll
            for (int j = 0; j < 8; ++j) {
                s0 += bf2f(r[j].x); s1 += bf2f(r[j].y);
                s2 += bf2f(r[j].z); s3 += bf2f(r[j].w);
            }
            p += 8;
        }
        while (p < p1) {
            ushort4 r = Yp[(long)srcs[p] << 5];
            s0 += bf2f(r.x); s1 += bf2f(r.y); s2 += bf2f(r.z); s3 += bf2f(r.w);
            ++p;
        }
        *reinterpret_cast<float4*>(H + ((long)n << 7) + (ll << 2)) = make_float4(s0, s1, s2, s3);
    } else {
        const unsigned* Yp = reinterpret_cast<const unsigned*>(Y) + ll;
        unsigned a = Yp[(long)n << 5];
        float s0 = bf2f((unsigned short)a), s1 = bf2f((unsigned short)(a >> 16));
        while (p + 8 <= p1) {
            unsigned r[8];
#pragma unroll
            for (int j = 0; j < 8; ++j) r[j] = Yp[(long)srcs[p + j] << 5];
#pragma unroll
            for (int j = 0; j < 8; ++j) {
                s0 += bf2f((unsigned short)r[j]);
                s1 += bf2f((unsigned short)(r[j] >> 16));
            }
            p += 8;
        }
        while (p < p1) {
            unsigned r = Yp[(long)srcs[p] << 5];
            s0 += bf2f((unsigned short)r);
            s1 += bf2f((unsigned short)(r >> 16));
            ++p;
        }
        *reinterpret_cast<float2*>(H + ((long)n << 6) + (ll << 1)) = make_float2(s0, s1);
    }
}

// ---------- BN stats, two-stage deterministic ----------
template <int C>
__global__ void k_bnstats1(const float* __restrict__ h, float* __restrict__ parts, int N) {
    constexpr int RPB = 256 / C;
    constexpr int LGC = (C == 128) ? 7 : 6;
    __shared__ float ts[256], ts2[256];
    int tid = threadIdx.x;
    int c = tid & (C - 1);
    float s = 0.f, s2 = 0.f;
    for (int n = blockIdx.x * RPB + (tid >> LGC); n < N; n += 256 * RPB) {
        float v = h[((long)n << LGC) + c];
        s += v;
        s2 = fmaf(v, v, s2);
    }
    ts[tid] = s;
    ts2[tid] = s2;
    __syncthreads();
    if (tid < C) {
#pragma unroll
        for (int i = 1; i < RPB; ++i) {
            s += ts[tid + i * C];
            s2 += ts2[tid + i * C];
        }
        parts[blockIdx.x * 2 * C + tid] = s;
        parts[blockIdx.x * 2 * C + C + tid] = s2;
    }
}

template <int C>
__global__ void k_bnstats2(const float* __restrict__ parts, const float* __restrict__ g,
                           const float* __restrict__ beta, float* __restrict__ stats,
                           float invN) {
    int c = threadIdx.x;
    float s = 0.f, s2 = 0.f;
    for (int b = 0; b < 256; ++b) {
        s += parts[b * 2 * C + c];
        s2 += parts[b * 2 * C + C + c];
    }
    float m = s * invN;
    float v = s2 * invN - m * m;
    float sc = g[c] * rsqrtf(v + 1e-5f);
    stats[2 * C + c] = sc;
    stats[3 * C + c] = beta[c] - m * sc;
}

// y = relu(h*scale + shift); optionally also emit bf16 copy
template <bool EMIT_B>
__global__ void k_bnapply(const float* __restrict__ h, const float* __restrict__ stats,
                          float* __restrict__ y, unsigned short* __restrict__ yb,
                          int N, int lgC) {
    int idx = blockIdx.x * blockDim.x + threadIdx.x;
    int C = 1 << lgC;
    int q = C >> 2;
    if (idx >= N * q) return;
    int n = idx >> (lgC - 2);
    int c4 = (idx & (q - 1)) << 2;
    const float4 hv = *reinterpret_cast<const float4*>(h + ((long)n << lgC) + c4);
    const float4 sc = *reinterpret_cast<const float4*>(stats + 2 * C + c4);
    const float4 sh = *reinterpret_cast<const float4*>(stats + 3 * C + c4);
    float4 o;
    o.x = fmaxf(fmaf(hv.x, sc.x, sh.x), 0.f);
    o.y = fmaxf(fmaf(hv.y, sc.y, sh.y), 0.f);
    o.z = fmaxf(fmaf(hv.z, sc.z, sh.z), 0.f);
    o.w = fmaxf(fmaf(hv.w, sc.w, sh.w), 0.f);
    *reinterpret_cast<float4*>(y + ((long)n << lgC) + c4) = o;
    if (EMIT_B) {
        ushort4 ob = make_ushort4(f2bf(o.x), f2bf(o.y), f2bf(o.z), f2bf(o.w));
        *reinterpret_cast<ushort4*>(yb + ((long)n << lgC) + c4) = ob;
    }
}

static inline int cdiv(long a, int b) { return (int)((a + b - 1) / b); }

extern "C" void kernel_launch(void* const* d_in, const int* in_sizes, int n_in,
                              void* d_out, int out_size, void* d_ws, size_t ws_size,
                              hipStream_t stream) {
    const float* ft0 = (const float*)d_in[0];
    const float* ft1 = (const float*)d_in[1];
    const float* fs  = (const float*)d_in[2];
    const int* et0 = (const int*)d_in[3];
    const int* et1 = (const int*)d_in[4];
    const int* es  = (const int*)d_in[5];
    const float* aT0_W = (const float*)d_in[6];
    const float* aT0_b = (const float*)d_in[7];
    const float* aT0_g = (const float*)d_in[8];
    const float* aT0_be = (const float*)d_in[9];
    const float* aT1_W = (const float*)d_in[10];
    const float* aT1_b = (const float*)d_in[11];
    const float* aT1_g = (const float*)d_in[12];
    const float* aT1_be = (const float*)d_in[13];
    const float* aS_W = (const float*)d_in[14];
    const float* aS_b = (const float*)d_in[15];
    const float* aS_g = (const float*)d_in[16];
    const float* aS_be = (const float*)d_in[17];
    const float* ext_W = (const float*)d_in[18];
    const float* ext_b = (const float*)d_in[19];
    const float* ext_g = (const float*)d_in[20];
    const float* ext_be = (const float*)d_in[21];
    const float* rT0_W = (const float*)d_in[22];
    const float* rT0_b = (const float*)d_in[23];
    const float* rT1_W = (const float*)d_in[24];
    const float* rT1_b = (const float*)d_in[25];

    const int N = in_sizes[0] / 256;
    const int E = in_sizes[3] / 2;
    const int NB = cdiv(N, 256);
    const int nC = cdiv(E, CPE);
    const int MT = N / 16;

    float* out = (float*)d_out;
    float* o_hs = out;                      // [N,64]
    float* o_h0 = out + (long)N * 64;       // [N,64]
    float* o_h1 = out + (long)N * 128;      // [N,64]
    float* o_f0 = out + (long)N * 192;      // [N,256]
    float* o_f1 = out + (long)N * 448;      // [N,128]

    // L1 pre-BN activations live in the (not yet written) f0/f1 regions
    float* H0 = o_f0;                       // [N,128]
    float* H1 = o_f0 + (long)N * 128;       // [N,128]
    float* HS = o_f1;                       // [N,128]

    // workspace
    char* p = (char*)d_ws;
    unsigned short* Yb = (unsigned short*)p; p += (size_t)N * 128 * 2;
    float* h2 = (float*)p;     p += (size_t)N * 64 * 4;
    unsigned short* ob0 = (unsigned short*)p; p += (size_t)N * 64 * 2;
    unsigned short* ob1 = (unsigned short*)p; p += (size_t)N * 64 * 2;
    int* rp   = (int*)p;       p += (size_t)3 * (N + 1) * 4;
    int* sr   = (int*)p;       p += (size_t)3 * E * 4;
    unsigned* part = (unsigned*)p; p += (size_t)3 * E * 4;
    int* cnt  = (int*)p;       p += (size_t)3 * NB * nC * 4;
    int* ofs  = (int*)p;       p += (size_t)3 * NB * nC * 4;
    int* tot  = (int*)p;       p += (size_t)3 * NB * 4;
    int* baseE = (int*)p;      p += (size_t)3 * (NB + 1) * 4;
    unsigned short* aT0b = (unsigned short*)p; p += 256 * 128 * 2;
    unsigned short* aT1b = (unsigned short*)p; p += 128 * 128 * 2;
    unsigned short* aSb  = (unsigned short*)p; p += 256 * 128 * 2;
    unsigned short* extb = (unsigned short*)p; p += 128 * 64 * 2;
    unsigned short* rT0b = (unsigned short*)p; p += 64 * 256 * 2;
    unsigned short* rT1b = (unsigned short*)p; p += 64 * 128 * 2;
    float* st0 = (float*)p;    p += 4 * 128 * 4;
    float* st1 = (float*)p;    p += 4 * 128 * 4;
    float* sts = (float*)p;    p += 4 * 128 * 4;
    float* st2 = (float*)p;    p += 4 * 64 * 4;
    float* PARTS = (float*)p;  p += 256 * 256 * 4;

    int* rp0 = rp, *rp1 = rp + (N + 1), *rps = rp + 2 * (N + 1);
    int* sr0 = sr, *sr1 = sr + E, *srs = sr + 2 * E;

    // ---- CSR build (counting sort by coarse bucket) ----
    k_p1<<<3 * nC, 256, 0, stream>>>(et0, et1, es, cnt, E, nC, NB);
    k_p2a<<<3 * NB, 256, 0, stream>>>(cnt, tot, nC);
    k_p2b<<<3, 256, 0, stream>>>(tot, baseE, rp, E, N, NB);
    k_p2c<<<3 * NB, 256, 0, stream>>>(cnt, baseE, ofs, nC, NB);
    k_p3<<<3 * nC, 256, 0, stream>>>(et0, et1, es, ofs, part, E, nC, NB);
    k_p4<<<3 * NB, 256, 0, stream>>>(part, baseE, rp, sr, E, N, NB);

    // ---- weight converts (fp32 -> bf16, original [Cout,Cin] layout) ----
    auto WC = [&](const float* W, unsigned short* Wb, int sz) {
        k_wcvt<<<cdiv(sz, 256), 256, 0, stream>>>(W, Wb, sz);
    };
    WC(aT0_W, aT0b, 256 * 128);
    WC(aT1_W, aT1b, 128 * 128);
    WC(aS_W, aSb, 256 * 128);
    WC(ext_W, extb, 128 * 64);
    WC(rT0_W, rT0b, 64 * 256);
    WC(rT1_W, rT1b, 64 * 128);

    // ---- layer 1: Yb = bf16(x @ Wt + b) via MFMA; H = Yb[n] + agg(Yb); stats ----
    auto layer1 = [&](const float* x, const unsigned short* Wb_, const float* b,
                      const float* g, const float* be, int Cin,
                      const int* rpg, const int* srg, float* H, float* st) {
        int blocks = cdiv((long)MT * 2, 4);
        if (Cin == 256)
            k_gemm<256, 2, false, false, true><<<blocks, 256, 0, stream>>>(x, nullptr, Wb_, b, Yb, MT);
        else
            k_gemm<128, 2, false, false, true><<<blocks, 256, 0, stream>>>(x, nullptr, Wb_, b, Yb, MT);
        k_aggb<128><<<cdiv(N, 8), 256, 0, stream>>>(Yb, rpg, srg, H, N);
        k_bnstats1<128><<<256, 256, 0, stream>>>(H, PARTS, N);
        k_bnstats2<128><<<1, 128, 0, stream>>>(PARTS, g, be, st, 1.0f / N);
    };
    layer1(ft0, aT0b, aT0_b, aT0_g, aT0_be, 256, rp0, sr0, H0, st0);
    layer1(ft1, aT1b, aT1_b, aT1_g, aT1_be, 128, rp1, sr1, H1, st1);
    layer1(fs,  aSb,  aS_b,  aS_g,  aS_be,  256, rps, srs, HS, sts);

    // ---- layer 2: Yb = bf16(bnrelu(H) @ extt + b) via MFMA; h2 = agg(Yb); bn-apply ----
    auto layer2 = [&](const float* H, const float* st, const int* rpg, const int* srg,
                      float* o_h, unsigned short* o_hb) {
        int blocks = cdiv((long)MT, 4);
        k_gemm<128, 1, true, false, true><<<blocks, 256, 0, stream>>>(H, st, extb, ext_b, Yb, MT);
        k_aggb<64><<<cdiv(N, 8), 256, 0, stream>>>(Yb, rpg, srg, h2, N);
        k_bnstats1<64><<<256, 256, 0, stream>>>(h2, PARTS, N);
        k_bnstats2<64><<<1, 64, 0, stream>>>(PARTS, ext_g, ext_be, st2, 1.0f / N);
        if (o_hb)
            k_bnapply<true><<<cdiv((long)N * 16, 256), 256, 0, stream>>>(h2, st2, o_h, o_hb, N, 6);
        else
            k_bnapply<false><<<cdiv((long)N * 16, 256), 256, 0, stream>>>(h2, st2, o_h, nullptr, N, 6);
    };
    layer2(H0, st0, rp0, sr0, o_h0, ob0);
    layer2(H1, st1, rp1, sr1, o_h1, ob1);
    layer2(HS, sts, rps, srs, o_hs, nullptr);

    // ---- layer 3: G = agg(bf16 o_h); f = relu(G @ Wt + b) via MFMA ----
    {
        k_aggb<64><<<cdiv(N, 8), 256, 0, stream>>>(ob0, rp0, sr0, h2, N);
        k_gemm<64, 4, false, true, false><<<cdiv((long)MT * 4, 4), 256, 0, stream>>>(h2, nullptr, rT0b, rT0_b, o_f0, MT);
        k_aggb<64><<<cdiv(N, 8), 256, 0, stream>>>(ob1, rp1, sr1, h2, N);
        k_gemm<64, 2, false, true, false><<<cdiv((long)MT * 2, 4), 256, 0, stream>>>(h2, nullptr, rT1b, rT1_b, o_f1, MT);
    }
}

// Round 10
// 514.659 us; speedup vs baseline: 26.7701x; 1.3997x over previous
//
#include <hip/hip_runtime.h>
#include <hip/hip_bf16.h>

#define CPE 8192   // edges per partition chunk

typedef short short8 __attribute__((ext_vector_type(8)));
typedef float f32x4 __attribute__((ext_vector_type(4)));
using u16 = unsigned short;

__device__ __forceinline__ float bf2f(u16 u) {
    return __uint_as_float(((unsigned)u) << 16);
}
__device__ __forceinline__ u16 f2bf(float f) {
    __hip_bfloat16 h = __float2bfloat16(f);   // RNE
    return *reinterpret_cast<u16*>(&h);
}

// ---------- batched weight convert: 6 fp32 arrays -> bf16 ----------
__global__ void k_wcvt6(const float* w0, const float* w1, const float* w2,
                        const float* w3, const float* w4, const float* w5,
                        u16* __restrict__ out,
                        int s0, int s1, int s2, int s3, int s4, int s5) {
    int i = blockIdx.x * blockDim.x + threadIdx.x;
    int b0 = s0, b1 = b0 + s1, b2 = b1 + s2, b3 = b2 + s3, b4 = b3 + s4, b5 = b4 + s5;
    if (i >= b5) return;
    const float* w;
    int o;
    if (i < b0) { w = w0; o = i; }
    else if (i < b1) { w = w1; o = i - b0; }
    else if (i < b2) { w = w2; o = i - b1; }
    else if (i < b3) { w = w3; o = i - b2; }
    else if (i < b4) { w = w4; o = i - b3; }
    else { w = w5; o = i - b4; }
    out[i] = f2bf(w[o]);
}

// ================= CSR build via coarse-bucket counting sort =================
// record u32 = ((dst & 255) << 16) | src   (requires N <= 65536)

__global__ void k_p1(const int* __restrict__ e0, const int* __restrict__ e1,
                     const int* __restrict__ e2, int* __restrict__ cnt,
                     int E, int nC, int NB) {
    __shared__ int h[256];
    int g = blockIdx.x / nC, c = blockIdx.x - g * nC;
    const int* dst = (g == 0 ? e0 : g == 1 ? e1 : e2) + E;
    for (int b = threadIdx.x; b < NB; b += 256) h[b] = 0;
    __syncthreads();
    int lo = c * CPE, hi = min(E, lo + CPE);
    for (int e = lo + threadIdx.x; e < hi; e += 256)
        atomicAdd(&h[dst[e] >> 8], 1);
    __syncthreads();
    for (int b = threadIdx.x; b < NB; b += 256)
        cnt[((long)g * NB + b) * nC + c] = h[b];
}

__global__ void k_p2a(const int* __restrict__ cnt, int* __restrict__ tot, int nC) {
    __shared__ int s[256];
    long gb = blockIdx.x;
    const int* row = cnt + gb * nC;
    int v = 0;
    for (int c = threadIdx.x; c < nC; c += 256) v += row[c];
    s[threadIdx.x] = v;
    __syncthreads();
    for (int o = 128; o > 0; o >>= 1) {
        if (threadIdx.x < o) s[threadIdx.x] += s[threadIdx.x + o];
        __syncthreads();
    }
    if (threadIdx.x == 0) tot[gb] = s[0];
}

__global__ void k_p2b(const int* __restrict__ tot, int* __restrict__ baseE,
                      int* __restrict__ rowptr, int E, int N, int NB) {
    __shared__ int s[256];
    int g = blockIdx.x, t = threadIdx.x;
    int v = (t < NB) ? tot[g * NB + t] : 0;
    s[t] = v;
    __syncthreads();
    for (int o = 1; o < 256; o <<= 1) {
        int a = (t >= o) ? s[t - o] : 0;
        __syncthreads();
        s[t] += a;
        __syncthreads();
    }
    if (t < NB) baseE[g * (NB + 1) + t] = s[t] - v;
    if (t == 0) {
        baseE[g * (NB + 1) + NB] = E;
        rowptr[(long)g * (N + 1) + N] = E;
    }
}

__global__ void k_p2c(const int* __restrict__ cnt, const int* __restrict__ baseE,
                      int* __restrict__ ofs, int nC, int NB) {
    __shared__ int s[256];
    long gb = blockIdx.x;
    int g = (int)(gb / NB), b = (int)(gb - (long)g * NB);
    int t = threadIdx.x;
    int v = (t < nC) ? cnt[gb * nC + t] : 0;
    s[t] = v;
    __syncthreads();
    for (int o = 1; o < 256; o <<= 1) {
        int a = (t >= o) ? s[t - o] : 0;
        __syncthreads();
        s[t] += a;
        __syncthreads();
    }
    if (t < nC) ofs[gb * nC + t] = baseE[g * (NB + 1) + b] + s[t] - v;
}

__global__ void k_p3(const int* __restrict__ e0, const int* __restrict__ e1,
                     const int* __restrict__ e2, const int* __restrict__ ofs,
                     unsigned* __restrict__ part, int E, int nC, int NB) {
    __shared__ int lbase[256];
    __shared__ int lcur[256];
    int g = blockIdx.x / nC, c = blockIdx.x - g * nC;
    const int* eg = (g == 0 ? e0 : g == 1 ? e1 : e2);
    const int* src = eg;
    const int* dst = eg + E;
    for (int b = threadIdx.x; b < NB; b += 256) {
        lbase[b] = ofs[((long)g * NB + b) * nC + c];
        lcur[b] = 0;
    }
    __syncthreads();
    int lo = c * CPE, hi = min(E, lo + CPE);
    unsigned* pg = part + (long)g * E;
    for (int e = lo + threadIdx.x; e < hi; e += 256) {
        int d = dst[e];
        int b = d >> 8;
        int pos = lbase[b] + atomicAdd(&lcur[b], 1);
        pg[pos] = ((unsigned)(d & 255) << 16) | (unsigned)src[e];
    }
}

__global__ void k_p4(const unsigned* __restrict__ part, const int* __restrict__ baseE,
                     int* __restrict__ rowptr, int* __restrict__ srcs,
                     int E, int N, int NB) {
    __shared__ int h[256];
    __shared__ int s[256];
    __shared__ int cur[256];
    int g = blockIdx.x / NB, b = blockIdx.x - g * NB;
    int n0 = b << 8;
    int nn = min(256, N - n0);
    int lo = baseE[g * (NB + 1) + b], hi = baseE[g * (NB + 1) + b + 1];
    int t = threadIdx.x;
    h[t] = 0;
    __syncthreads();
    const unsigned* pg = part + (long)g * E;
    for (int i = lo + t; i < hi; i += 256)
        atomicAdd(&h[pg[i] >> 16], 1);
    __syncthreads();
    int v = h[t];
    s[t] = v;
    __syncthreads();
    for (int o = 1; o < 256; o <<= 1) {
        int a = (t >= o) ? s[t - o] : 0;
        __syncthreads();
        s[t] += a;
        __syncthreads();
    }
    int excl = lo + s[t] - v;
    if (t < nn) rowptr[(long)g * (N + 1) + n0 + t] = excl;
    cur[t] = excl;
    __syncthreads();
    int* sg = srcs + (long)g * E;
    for (int i = lo + t; i < hi; i += 256) {
        unsigned r = pg[i];
        int pos = atomicAdd(&cur[r >> 16], 1);
        sg[pos] = (int)(r & 0xFFFFu);
    }
}

// ---------- MFMA GEMM core ----------
// A-frag: row = lane&15, k = (lane>>4)*8+j ; B (weights [COUT,CIN] bf16) same form.
// D: row = (lane>>4)*4 + r, col = lane&15.
template <bool ABF, bool BN_IN, bool RELU_OUT, bool BF16_OUT>
__device__ __forceinline__ void gemm_body(const void* X, const float* stats,
                                          const u16* __restrict__ Wb,
                                          const float* __restrict__ bias,
                                          void* Yv, int MT, int Cin, int SH,
                                          int wl, int l) {
    int mt = wl >> SH;
    if (mt >= MT) return;
    int CG = 1 << SH;
    int COUT = CG * 64;
    int cg = wl & (CG - 1);
    int lm = l & 15, lh = l >> 4;
    int kb = lh * 8;

    const float* xrf = nullptr;
    const u16* xrb = nullptr;
    if (ABF) xrb = (const u16*)X + (long)(mt * 16 + lm) * Cin + kb;
    else     xrf = (const float*)X + (long)(mt * 16 + lm) * Cin + kb;
    const u16* wp[4];
#pragma unroll
    for (int t = 0; t < 4; ++t)
        wp[t] = Wb + (long)(cg * 64 + t * 16 + lm) * Cin + kb;
    const float* scp = nullptr;
    const float* shp = nullptr;
    if (BN_IN) {
        scp = stats + 2 * Cin + kb;
        shp = stats + 3 * Cin + kb;
    }

    f32x4 acc[4];
#pragma unroll
    for (int t = 0; t < 4; ++t) acc[t] = (f32x4){0.f, 0.f, 0.f, 0.f};

    for (int k0 = 0; k0 < Cin; k0 += 32) {
        short8 a;
        if (ABF) {
            short8 raw = *reinterpret_cast<const short8*>(xrb);
            if (BN_IN) {
#pragma unroll
                for (int j = 0; j < 8; ++j) {
                    float x = bf2f((u16)raw[j]);
                    x = fmaxf(fmaf(x, scp[j], shp[j]), 0.f);
                    a[j] = (short)f2bf(x);
                }
                scp += 32; shp += 32;
            } else {
                a = raw;
            }
            xrb += 32;
        } else {
            float4 x0 = *reinterpret_cast<const float4*>(xrf);
            float4 x1 = *reinterpret_cast<const float4*>(xrf + 4);
            if (BN_IN) {
                float4 s0 = *reinterpret_cast<const float4*>(scp);
                float4 s1 = *reinterpret_cast<const float4*>(scp + 4);
                float4 h0 = *reinterpret_cast<const float4*>(shp);
                float4 h1 = *reinterpret_cast<const float4*>(shp + 4);
                x0.x = fmaxf(fmaf(x0.x, s0.x, h0.x), 0.f);
                x0.y = fmaxf(fmaf(x0.y, s0.y, h0.y), 0.f);
                x0.z = fmaxf(fmaf(x0.z, s0.z, h0.z), 0.f);
                x0.w = fmaxf(fmaf(x0.w, s0.w, h0.w), 0.f);
                x1.x = fmaxf(fmaf(x1.x, s1.x, h1.x), 0.f);
                x1.y = fmaxf(fmaf(x1.y, s1.y, h1.y), 0.f);
                x1.z = fmaxf(fmaf(x1.z, s1.z, h1.z), 0.f);
                x1.w = fmaxf(fmaf(x1.w, s1.w, h1.w), 0.f);
                scp += 32; shp += 32;
            }
            a[0] = (short)f2bf(x0.x); a[1] = (short)f2bf(x0.y);
            a[2] = (short)f2bf(x0.z); a[3] = (short)f2bf(x0.w);
            a[4] = (short)f2bf(x1.x); a[5] = (short)f2bf(x1.y);
            a[6] = (short)f2bf(x1.z); a[7] = (short)f2bf(x1.w);
            xrf += 32;
        }
#pragma unroll
        for (int t = 0; t < 4; ++t) {
            short8 b = *reinterpret_cast<const short8*>(wp[t]);
            acc[t] = __builtin_amdgcn_mfma_f32_16x16x32_bf16(a, b, acc[t], 0, 0, 0);
            wp[t] += 32;
        }
    }

    int nb = mt * 16 + lh * 4;
#pragma unroll
    for (int t = 0; t < 4; ++t) {
        int col = cg * 64 + t * 16 + lm;
        float bi = bias[col];
#pragma unroll
        for (int r = 0; r < 4; ++r) {
            float v = acc[t][r] + bi;
            if (RELU_OUT) v = fmaxf(v, 0.f);
            if (BF16_OUT)
                ((u16*)Yv)[(long)(nb + r) * COUT + col] = f2bf(v);
            else
                ((float*)Yv)[(long)(nb + r) * COUT + col] = v;
        }
    }
}

// L1: 3 graphs, A fp32, runtime Cin, CG=2, bf16 out
__global__ __launch_bounds__(256) void k_gemmL1(
        const float* x0, const float* x1, const float* x2,
        const u16* w0, const u16* w1, const u16* w2,
        const float* b0, const float* b1, const float* b2,
        u16* Yb, int MT, int N, int B1) {
    int g = blockIdx.x / B1;
    int wl = (blockIdx.x - g * B1) * 4 + (threadIdx.x >> 6);
    const float* x = g == 0 ? x0 : (g == 1 ? x1 : x2);
    const u16* w = g == 0 ? w0 : (g == 1 ? w1 : w2);
    const float* b = g == 0 ? b0 : (g == 1 ? b1 : b2);
    int cin = (g == 1) ? 128 : 256;
    gemm_body<false, false, false, true>(x, nullptr, w, b, Yb + (long)g * N * 128,
                                         MT, cin, 1, wl, threadIdx.x & 63);
}

// L2: 3 graphs, A bf16 + BN_IN, shared weights, CG=1 (Cout 64), bf16 out
// NOTE: output stride between graphs is N*64 (COUT=64) to match k_aggb3<64>.
__global__ __launch_bounds__(256) void k_gemmL2(
        const u16* Hb, const float* ST, const u16* wext, const float* bext,
        u16* Yb, int MT, int N, int B2) {
    int g = blockIdx.x / B2;
    int wl = (blockIdx.x - g * B2) * 4 + (threadIdx.x >> 6);
    gemm_body<true, true, false, true>(Hb + (long)g * N * 128, ST + g * 512, wext,
                                       bext, Yb + (long)g * N * 64, MT, 128, 0,
                                       wl, threadIdx.x & 63);
}

// L3: 2 graphs, A bf16, fp32 relu out; g0: CG=4 Cout256 -> f0, g1: CG=2 Cout128 -> f1
__global__ __launch_bounds__(256) void k_gemmL3(
        const u16* h3, const u16* wr0, const u16* wr1,
        const float* br0, const float* br1,
        float* f0, float* f1, int MT, int N, int B0) {
    int b = blockIdx.x;
    int g = (b < B0) ? 0 : 1;
    int wl = (g == 0 ? b : b - B0) * 4 + (threadIdx.x >> 6);
    if (g == 0)
        gemm_body<true, false, true, false>(h3, nullptr, wr0, br0, f0, MT, 64, 2,
                                            wl, threadIdx.x & 63);
    else
        gemm_body<true, false, true, false>(h3 + (long)N * 64, nullptr, wr1, br1,
                                            f1, MT, 64, 1, wl, threadIdx.x & 63);
}

// ---------- batched aggregation: out[n] = in[n] + sum_{e} in[src[e]] (bf16 in/out, fp32 acc) ----------
template <int CH>  // 128 or 64
__global__ void k_aggb3(const u16* __restrict__ in, const int* __restrict__ rp,
                        const int* __restrict__ sr, u16* __restrict__ outb,
                        int N, int E, int BPG) {
    int g = blockIdx.x / BPG;
    int bb = blockIdx.x - g * BPG;
    int l = threadIdx.x & 63;
    int ll = l & 31;
    int n = (bb << 3) + ((threadIdx.x >> 6) << 1) + (l >> 5);
    if (n >= N) return;
    const int* rowptr = rp + (long)g * (N + 1);
    const int* srcs = sr + (long)g * E;
    int p = rowptr[n], p1 = rowptr[n + 1];
    if constexpr (CH == 128) {
        const ushort4* Yp = reinterpret_cast<const ushort4*>(in + (long)g * N * 128) + ll;
        ushort4 a = Yp[(long)n << 5];
        float s0 = bf2f(a.x), s1 = bf2f(a.y), s2 = bf2f(a.z), s3 = bf2f(a.w);
        while (p + 8 <= p1) {
            ushort4 r[8];
#pragma unroll
            for (int j = 0; j < 8; ++j) r[j] = Yp[(long)srcs[p + j] << 5];
#pragma unroll
            for (int j = 0; j < 8; ++j) {
                s0 += bf2f(r[j].x); s1 += bf2f(r[j].y);
                s2 += bf2f(r[j].z); s3 += bf2f(r[j].w);
            }
            p += 8;
        }
        while (p < p1) {
            ushort4 r = Yp[(long)srcs[p] << 5];
            s0 += bf2f(r.x); s1 += bf2f(r.y); s2 += bf2f(r.z); s3 += bf2f(r.w);
            ++p;
        }
        ushort4 o = make_ushort4(f2bf(s0), f2bf(s1), f2bf(s2), f2bf(s3));
        (reinterpret_cast<ushort4*>(outb + (long)g * N * 128) + ll)[(long)n << 5] = o;
    } else {
        const unsigned* Yp = reinterpret_cast<const unsigned*>(in + (long)g * N * 64) + ll;
        unsigned a = Yp[(long)n << 5];
        float s0 = bf2f((u16)a), s1 = bf2f((u16)(a >> 16));
        while (p + 8 <= p1) {
            unsigned r[8];
#pragma unroll
            for (int j = 0; j < 8; ++j) r[j] = Yp[(long)srcs[p + j] << 5];
#pragma unroll
            for (int j = 0; j < 8; ++j) {
                s0 += bf2f((u16)r[j]);
                s1 += bf2f((u16)(r[j] >> 16));
            }
            p += 8;
        }
        while (p < p1) {
            unsigned r = Yp[(long)srcs[p] << 5];
            s0 += bf2f((u16)r);
            s1 += bf2f((u16)(r >> 16));
            ++p;
        }
        unsigned o = (unsigned)f2bf(s0) | ((unsigned)f2bf(s1) << 16);
        (reinterpret_cast<unsigned*>(outb + (long)g * N * 64) + ll)[(long)n << 5] = o;
    }
}

// ---------- BN stats (bf16 input), two-stage deterministic, batched ----------
template <int C>
__global__ void k_bnstats1(const u16* __restrict__ h, float* __restrict__ parts,
                           int N, int PSTRIDE) {
    constexpr int RPB = 256 / C;
    constexpr int LGC = (C == 128) ? 7 : 6;
    __shared__ float ts[256], ts2[256];
    int g = blockIdx.x >> 8;
    int blk = blockIdx.x & 255;
    const u16* hg = h + (long)g * N * C;
    float* pg = parts + (long)g * PSTRIDE;
    int tid = threadIdx.x;
    int c = tid & (C - 1);
    float s = 0.f, s2 = 0.f;
    for (int n = blk * RPB + (tid >> LGC); n < N; n += 256 * RPB) {
        float v = bf2f(hg[((long)n << LGC) + c]);
        s += v;
        s2 = fmaf(v, v, s2);
    }
    ts[tid] = s;
    ts2[tid] = s2;
    __syncthreads();
    if (tid < C) {
#pragma unroll
        for (int i = 1; i < RPB; ++i) {
            s += ts[tid + i * C];
            s2 += ts2[tid + i * C];
        }
        pg[blk * 2 * C + tid] = s;
        pg[blk * 2 * C + C + tid] = s2;
    }
}

template <int C>
__global__ void k_bnstats2(const float* __restrict__ parts,
                           const float* g0, const float* g1, const float* g2,
                           const float* b0, const float* b1, const float* b2,
                           float* __restrict__ ST, float invN, int PSTRIDE) {
    int g = blockIdx.x;
    const float* gam = g == 0 ? g0 : (g == 1 ? g1 : g2);
    const float* bet = g == 0 ? b0 : (g == 1 ? b1 : b2);
    const float* pg = parts + (long)g * PSTRIDE;
    float* st = ST + g * 4 * C;
    int c = threadIdx.x;
    float s = 0.f, s2 = 0.f;
    for (int b = 0; b < 256; ++b) {
        s += pg[b * 2 * C + c];
        s2 += pg[b * 2 * C + C + c];
    }
    float m = s * invN;
    float v = s2 * invN - m * m;
    float sc = gam[c] * rsqrtf(v + 1e-5f);
    st[2 * C + c] = sc;
    st[3 * C + c] = bet[c] - m * sc;
}

// ---------- batched BN apply (bf16 in, fp32 out + bf16 copy for g<2) ----------
__global__ void k_bnapply3(const u16* __restrict__ h2b, const float* __restrict__ ST2,
                           float* __restrict__ out, u16* __restrict__ obb,
                           int N, int BPG) {
    int g = blockIdx.x / BPG;
    int idx = (blockIdx.x - g * BPG) * 256 + threadIdx.x;
    if (idx >= N * 16) return;
    int n = idx >> 4;
    int c4 = (idx & 15) << 2;
    const u16* hg = h2b + (long)g * N * 64;
    const float* st = ST2 + g * 256;
    ushort4 hv = *reinterpret_cast<const ushort4*>(hg + ((long)n << 6) + c4);
    const float4 sc = *reinterpret_cast<const float4*>(st + 128 + c4);
    const float4 sh = *reinterpret_cast<const float4*>(st + 192 + c4);
    float4 o;
    o.x = fmaxf(fmaf(bf2f(hv.x), sc.x, sh.x), 0.f);
    o.y = fmaxf(fmaf(bf2f(hv.y), sc.y, sh.y), 0.f);
    o.z = fmaxf(fmaf(bf2f(hv.z), sc.z, sh.z), 0.f);
    o.w = fmaxf(fmaf(bf2f(hv.w), sc.w, sh.w), 0.f);
    // g0 -> o_h0 (out + N*64), g1 -> o_h1 (out + 2N*64), g2(s) -> o_hs (out)
    float* yb = (g == 0) ? out + (long)N * 64 : (g == 1) ? out + (long)N * 128 : out;
    *reinterpret_cast<float4*>(yb + ((long)n << 6) + c4) = o;
    if (g < 2) {
        ushort4 ob = make_ushort4(f2bf(o.x), f2bf(o.y), f2bf(o.z), f2bf(o.w));
        *reinterpret_cast<ushort4*>(obb + (long)g * N * 64 + ((long)n << 6) + c4) = ob;
    }
}

static inline int cdiv(long a, int b) { return (int)((a + b - 1) / b); }

extern "C" void kernel_launch(void* const* d_in, const int* in_sizes, int n_in,
                              void* d_out, int out_size, void* d_ws, size_t ws_size,
                              hipStream_t stream) {
    const float* ft0 = (const float*)d_in[0];
    const float* ft1 = (const float*)d_in[1];
    const float* fs  = (const float*)d_in[2];
    const int* et0 = (const int*)d_in[3];
    const int* et1 = (const int*)d_in[4];
    const int* es  = (const int*)d_in[5];
    const float* aT0_W = (const float*)d_in[6];
    const float* aT0_b = (const float*)d_in[7];
    const float* aT0_g = (const float*)d_in[8];
    const float* aT0_be = (const float*)d_in[9];
    const float* aT1_W = (const float*)d_in[10];
    const float* aT1_b = (const float*)d_in[11];
    const float* aT1_g = (const float*)d_in[12];
    const float* aT1_be = (const float*)d_in[13];
    const float* aS_W = (const float*)d_in[14];
    const float* aS_b = (const float*)d_in[15];
    const float* aS_g = (const float*)d_in[16];
    const float* aS_be = (const float*)d_in[17];
    const float* ext_W = (const float*)d_in[18];
    const float* ext_b = (const float*)d_in[19];
    const float* ext_g = (const float*)d_in[20];
    const float* ext_be = (const float*)d_in[21];
    const float* rT0_W = (const float*)d_in[22];
    const float* rT0_b = (const float*)d_in[23];
    const float* rT1_W = (const float*)d_in[24];
    const float* rT1_b = (const float*)d_in[25];

    const int N = in_sizes[0] / 256;
    const int E = in_sizes[3] / 2;
    const int NB = cdiv(N, 256);
    const int nC = cdiv(E, CPE);
    const int MT = N / 16;

    float* out = (float*)d_out;
    float* o_f0 = out + (long)N * 192;      // [N,256]
    float* o_f1 = out + (long)N * 448;      // [N,128]

    // workspace
    char* p = (char*)d_ws;
    u16* Yb  = (u16*)p;        p += (size_t)3 * N * 128 * 2;   // L1/L2 gemm outputs
    u16* Hb  = (u16*)p;        p += (size_t)3 * N * 128 * 2;   // L1 pre-BN agg (bf16)
    u16* h2b = (u16*)p;        p += (size_t)3 * N * 64 * 2;    // L2 pre-BN agg / L3 agg
    u16* obb = (u16*)p;        p += (size_t)2 * N * 64 * 2;    // bf16 o_h0/o_h1
    int* rp   = (int*)p;       p += (size_t)3 * (N + 1) * 4;
    int* sr   = (int*)p;       p += (size_t)3 * E * 4;
    unsigned* part = (unsigned*)p; p += (size_t)3 * E * 4;
    int* cnt  = (int*)p;       p += (size_t)3 * NB * nC * 4;
    int* ofs  = (int*)p;       p += (size_t)3 * NB * nC * 4;
    int* tot  = (int*)p;       p += (size_t)3 * NB * 4;
    int* baseE = (int*)p;      p += (size_t)3 * (NB + 1) * 4;
    u16* WBF = (u16*)p;        p += (size_t)(256*128 + 128*128 + 256*128 + 128*64 + 64*256 + 64*128) * 2;
    float* ST1 = (float*)p;    p += (size_t)3 * 512 * 4;
    float* ST2 = (float*)p;    p += (size_t)3 * 256 * 4;
    float* PARTS = (float*)p;  p += (size_t)3 * 256 * 256 * 4;

    u16* aT0b = WBF;
    u16* aT1b = aT0b + 256 * 128;
    u16* aSb  = aT1b + 128 * 128;
    u16* extb = aSb + 256 * 128;
    u16* rT0b = extb + 128 * 64;
    u16* rT1b = rT0b + 64 * 256;

    // ---- CSR build ----
    k_p1<<<3 * nC, 256, 0, stream>>>(et0, et1, es, cnt, E, nC, NB);
    k_p2a<<<3 * NB, 256, 0, stream>>>(cnt, tot, nC);
    k_p2b<<<3, 256, 0, stream>>>(tot, baseE, rp, E, N, NB);
    k_p2c<<<3 * NB, 256, 0, stream>>>(cnt, baseE, ofs, nC, NB);
    k_p3<<<3 * nC, 256, 0, stream>>>(et0, et1, es, ofs, part, E, nC, NB);
    k_p4<<<3 * NB, 256, 0, stream>>>(part, baseE, rp, sr, E, N, NB);

    // ---- weight converts (one launch) ----
    {
        int tot_w = 256*128 + 128*128 + 256*128 + 128*64 + 64*256 + 64*128;
        k_wcvt6<<<cdiv(tot_w, 256), 256, 0, stream>>>(
            aT0_W, aT1_W, aS_W, ext_W, rT0_W, rT1_W, WBF,
            256*128, 128*128, 256*128, 128*64, 64*256, 64*128);
    }

    const int B1 = cdiv((long)MT * 2, 4);
    const int B2 = cdiv((long)MT, 4);
    const int BPG = N / 8;           // agg blocks per graph (N % 8 == 0)
    const int BPA = cdiv((long)N * 16, 256);  // bnapply blocks per graph

    // ---- layer 1 ----
    k_gemmL1<<<3 * B1, 256, 0, stream>>>(ft0, ft1, fs, aT0b, aT1b, aSb,
                                         aT0_b, aT1_b, aS_b, Yb, MT, N, B1);
    k_aggb3<128><<<3 * BPG, 256, 0, stream>>>(Yb, rp, sr, Hb, N, E, BPG);
    k_bnstats1<128><<<3 * 256, 256, 0, stream>>>(Hb, PARTS, N, 256 * 256);
    k_bnstats2<128><<<3, 128, 0, stream>>>(PARTS, aT0_g, aT1_g, aS_g,
                                           aT0_be, aT1_be, aS_be, ST1, 1.0f / N, 256 * 256);

    // ---- layer 2 ----
    k_gemmL2<<<3 * B2, 256, 0, stream>>>(Hb, ST1, extb, ext_b, Yb, MT, N, B2);
    k_aggb3<64><<<3 * BPG, 256, 0, stream>>>(Yb, rp, sr, h2b, N, E, BPG);
    k_bnstats1<64><<<3 * 256, 256, 0, stream>>>(h2b, PARTS, N, 256 * 128);
    k_bnstats2<64><<<3, 64, 0, stream>>>(PARTS, ext_g, ext_g, ext_g,
                                         ext_be, ext_be, ext_be, ST2, 1.0f / N, 256 * 128);
    k_bnapply3<<<3 * BPA, 256, 0, stream>>>(h2b, ST2, out, obb, N, BPA);

    // ---- layer 3 ----
    k_aggb3<64><<<2 * BPG, 256, 0, stream>>>(obb, rp, sr, h2b, N, E, BPG);
    k_gemmL3<<<MT + cdiv((long)MT * 2, 4), 256, 0, stream>>>(
        h2b, rT0b, rT1b, rT0_b, rT1_b, o_f0, o_f1, MT, N, MT);
}